// Round 1
// baseline (439.450 us; speedup 1.0000x reference)
//
#include <hip/hip_runtime.h>

typedef __attribute__((ext_vector_type(8))) short short8;
typedef __attribute__((ext_vector_type(4))) float f32x4;

#define B_ 16
#define T_ 2000
#define E_ 512
#define A_ 512
#define H_ 4
#define C_ 10
#define KW_ 201
#define KTOT 544   // 512 enc + 10 conv + 22 zero pad
#define NKS 17     // 544 / 32
#define TM 64      // rows (b,t) per block
#define AROW 552   // padded LDS row stride (ushorts) for A tile
#define BROW 40    // padded LDS row stride (ushorts) for B tile (32 + 8)

__device__ __forceinline__ unsigned short f2bf(float f){
  unsigned int u = __float_as_uint(f);
  u += 0x7FFFu + ((u >> 16) & 1u);   // round-to-nearest-even
  return (unsigned short)(u >> 16);
}

__device__ __forceinline__ float fast_tanh(float x){
  float e2 = __expf(2.f * x);
  return 1.f - __fdividef(2.f, e2 + 1.f);
}

// ---------------------------------------------------------------------------
// Build combined B matrix, k-major bf16: Wcomb[h][a][k], k<512: W_enc[h][k][a],
// 512<=k<522: W_conv[h][k-512][a], else 0.
__global__ void k_wcomb(const float* __restrict__ We, const float* __restrict__ Wc,
                        unsigned short* __restrict__ Wcomb){
  int h = blockIdx.z, a0 = blockIdx.y * 32, k0 = blockIdx.x * 32;
  __shared__ float t[32][33];
  int tx = threadIdx.x, ty = threadIdx.y; // 32 x 8
  for (int i = ty; i < 32; i += 8){
    int k = k0 + i;
    float v = 0.f;
    if (k < 512)      v = We[((size_t)(h*512) + k)*512 + a0 + tx];
    else if (k < 522) v = Wc[((size_t)(h*10) + (k-512))*512 + a0 + tx];
    t[i][tx] = v;
  }
  __syncthreads();
  for (int i = ty; i < 32; i += 8){
    Wcomb[((size_t)(h*512) + a0 + i)*KTOT + k0 + tx] = f2bf(t[tx][i]);
  }
}

// ---------------------------------------------------------------------------
// dech[b][h][a] = b_enc[h][a] + sum_d dec_out[b][d] * W_dec[h][d][a]
__global__ void k_dec(const float* __restrict__ dec, const float* __restrict__ Wd,
                      const float* __restrict__ be, float* __restrict__ dech){
  int bh = blockIdx.x; int b = bh >> 2, h = bh & 3;
  int a0 = threadIdx.x * 2;
  float acc0 = be[h*512 + a0], acc1 = be[h*512 + a0 + 1];
  const float* w = Wd + (size_t)h*512*512;
  const float* dv = dec + b*512;
  for (int d = 0; d < 512; d++){
    float x = dv[d];
    acc0 = fmaf(x, w[(size_t)d*512 + a0],     acc0);
    acc1 = fmaf(x, w[(size_t)d*512 + a0 + 1], acc1);
  }
  dech[(size_t)bh*512 + a0]     = acc0;
  dech[(size_t)bh*512 + a0 + 1] = acc1;
}

// ---------------------------------------------------------------------------
// conv_feat[b][t][h][c] = sum_k aw_step[b][t+k-100][h] * conv_w[h*10+c][0][k]
#define TCH 250
__global__ void k_conv(const float* __restrict__ aw_step, const float* __restrict__ conv_w,
                       float* __restrict__ conv_feat){
  int tc = blockIdx.x, h = blockIdx.y, b = blockIdx.z;
  int t0 = tc * TCH;
  __shared__ float awl[TCH + 200];
  __shared__ float wl[C_][KW_];
  int tid = threadIdx.x;
  for (int i = tid; i < TCH + 200; i += 256){
    int t = t0 - 100 + i;
    awl[i] = (t >= 0 && t < T_) ? aw_step[((size_t)b*T_ + t)*H_ + h] : 0.f;
  }
  for (int i = tid; i < C_*KW_; i += 256){
    wl[i/KW_][i%KW_] = conv_w[(size_t)(h*C_ + i/KW_)*KW_ + i%KW_];
  }
  __syncthreads();
  for (int o = tid; o < TCH*C_; o += 256){
    int c = o / TCH, tl = o % TCH;
    float s = 0.f;
    #pragma unroll 4
    for (int k = 0; k < KW_; k++) s = fmaf(awl[tl + k], wl[c][k], s);
    conv_feat[(((size_t)b*T_ + t0 + tl)*H_ + h)*C_ + c] = s;
  }
}

// ---------------------------------------------------------------------------
// Fused energy GEMM: energy[b][t][h] = mask * sum_a tanh(enc@We + dec@Wd + conv@Wc)[a] * V[h][a]
__global__ __launch_bounds__(512, 1) void k_energy(
    const float* __restrict__ enc, const unsigned short* __restrict__ Wcomb,
    const float* __restrict__ conv_feat, const float* __restrict__ dech,
    const float* __restrict__ Vv, const int* __restrict__ x_lens,
    float* __restrict__ energy)
{
  __shared__ __align__(16) unsigned short As[TM * AROW];    // 70656 B
  __shared__ __align__(16) unsigned short Bs[512 * BROW];   // 40960 B
  __shared__ float e_red[TM];

  int tt = blockIdx.x, b = blockIdx.y;
  int t0 = tt * TM;
  int tid = threadIdx.x;
  int lane = tid & 63, w = tid >> 6;          // 8 waves, each owns 64 N-cols
  int xl = x_lens[b];

  // stage A (enc rows), k = 0..511, f32 -> bf16
  for (int idx = tid; idx < TM*128; idx += 512){
    int row = idx >> 7, c4 = idx & 127;
    int t = t0 + row;
    float4 v = make_float4(0.f, 0.f, 0.f, 0.f);
    if (t < T_) v = *(const float4*)&enc[((size_t)b*T_ + t)*E_ + c4*4];
    ushort4 u;
    u.x = f2bf(v.x); u.y = f2bf(v.y); u.z = f2bf(v.z); u.w = f2bf(v.w);
    *(ushort4*)&As[row*AROW + c4*4] = u;
  }

  for (int h = 0; h < H_; h++){
    __syncthreads();
    // stage A tail, k = 512..543 (conv features for this head)
    for (int idx = tid; idx < TM*32; idx += 512){
      int row = idx >> 5, kk = idx & 31;
      int t = t0 + row;
      float v = 0.f;
      if (kk < C_ && t < T_) v = conv_feat[(((size_t)b*T_ + t)*H_ + h)*C_ + kk];
      As[row*AROW + 512 + kk] = f2bf(v);
    }
    if (tid < TM) e_red[tid] = 0.f;

    f32x4 acc[4][4];
    #pragma unroll
    for (int m = 0; m < 4; m++){
      #pragma unroll
      for (int q = 0; q < 4; q++) acc[m][q] = (f32x4){0.f, 0.f, 0.f, 0.f};
    }

    for (int ks = 0; ks < NKS; ks++){
      int k0 = ks * 32;
      __syncthreads();
      { // stage B: Bs[n][kk] = Wcomb[h][n][k0+kk]
        int n = tid;
        const unsigned short* s0 = Wcomb + ((size_t)(h*512) + n)*KTOT + k0;
        const int4* s = (const int4*)s0;
        int4* d = (int4*)&Bs[n*BROW];
        d[0] = s[0]; d[1] = s[1]; d[2] = s[2]; d[3] = s[3];
      }
      __syncthreads();
      short8 af[4];
      #pragma unroll
      for (int m = 0; m < 4; m++)
        af[m] = *(const short8*)&As[(m*16 + (lane & 15))*AROW + k0 + (lane >> 4)*8];
      #pragma unroll
      for (int q = 0; q < 4; q++){
        short8 bf = *(const short8*)&Bs[(w*64 + q*16 + (lane & 15))*BROW + (lane >> 4)*8];
        #pragma unroll
        for (int m = 0; m < 4; m++)
          acc[m][q] = __builtin_amdgcn_mfma_f32_16x16x32_bf16(af[m], bf, acc[m][q], 0, 0, 0);
      }
    }
    __syncthreads();

    // epilogue: + dec bias, tanh, *V, reduce over a
    float dv[4], vv[4];
    #pragma unroll
    for (int q = 0; q < 4; q++){
      int a = w*64 + q*16 + (lane & 15);
      dv[q] = dech[((size_t)(b*H_) + h)*A_ + a];
      vv[q] = Vv[h*A_ + a];
    }
    #pragma unroll
    for (int m = 0; m < 4; m++){
      #pragma unroll
      for (int r = 0; r < 4; r++){
        float ps = 0.f;
        #pragma unroll
        for (int q = 0; q < 4; q++){
          float x = acc[m][q][r] + dv[q];
          ps = fmaf(fast_tanh(x), vv[q], ps);
        }
        ps += __shfl_xor(ps, 1);
        ps += __shfl_xor(ps, 2);
        ps += __shfl_xor(ps, 4);
        ps += __shfl_xor(ps, 8);
        if ((lane & 15) == 0){
          int row = m*16 + (lane >> 4)*4 + r;
          atomicAdd(&e_red[row], ps);
        }
      }
    }
    __syncthreads();
    if (tid < TM){
      int t = t0 + tid;
      if (t < T_) energy[((size_t)b*T_ + t)*H_ + h] = (t < xl) ? e_red[tid] : 0.f;
    }
  }
}

// ---------------------------------------------------------------------------
// softmax over T per (b,h); writes aw
__global__ void k_softmax(const float* __restrict__ energy, float* __restrict__ aw){
  int h = blockIdx.x, b = blockIdx.y;
  __shared__ float sh[T_];
  __shared__ float red[8];
  int tid = threadIdx.x;
  float mx = -1e30f;
  for (int t = tid; t < T_; t += 256){
    float e = energy[((size_t)b*T_ + t)*H_ + h];
    sh[t] = e;
    mx = fmaxf(mx, e);
  }
  #pragma unroll
  for (int o = 32; o; o >>= 1) mx = fmaxf(mx, __shfl_xor(mx, o));
  if ((tid & 63) == 0) red[tid >> 6] = mx;
  __syncthreads();
  mx = fmaxf(fmaxf(red[0], red[1]), fmaxf(red[2], red[3]));
  float sm = 0.f;
  for (int t = tid; t < T_; t += 256){
    float ex = __expf(sh[t] - mx);
    sh[t] = ex;
    sm += ex;
  }
  #pragma unroll
  for (int o = 32; o; o >>= 1) sm += __shfl_xor(sm, o);
  if ((tid & 63) == 0) red[4 + (tid >> 6)] = sm;
  __syncthreads();
  sm = red[4] + red[5] + red[6] + red[7];
  float inv = 1.f / sm;
  for (int t = tid; t < T_; t += 256){
    aw[((size_t)b*T_ + t)*H_ + h] = sh[t] * inv;
  }
}

// ---------------------------------------------------------------------------
// partial context: ctxp[b][ch][h][e] = sum_{t in chunk} enc[b][t][e]*aw[b][t][h]
#define CCH 125
__global__ void k_ctxp(const float* __restrict__ enc, const float* __restrict__ aw,
                       float* __restrict__ ctxp){
  int ch = blockIdx.x, b = blockIdx.y;
  int t0 = ch * CCH;
  __shared__ float awl[CCH * 4];
  int tid = threadIdx.x;
  for (int i = tid; i < CCH*4; i += 256)
    awl[i] = aw[((size_t)b*T_ + t0)*H_ + i];
  __syncthreads();
  int e0 = tid * 2;
  float a0x=0,a0y=0,a1x=0,a1y=0,a2x=0,a2y=0,a3x=0,a3y=0;
  for (int tl = 0; tl < CCH; tl++){
    float2 ev = *(const float2*)&enc[((size_t)b*T_ + t0 + tl)*E_ + e0];
    float w0 = awl[tl*4+0], w1 = awl[tl*4+1], w2 = awl[tl*4+2], w3 = awl[tl*4+3];
    a0x = fmaf(w0, ev.x, a0x); a0y = fmaf(w0, ev.y, a0y);
    a1x = fmaf(w1, ev.x, a1x); a1y = fmaf(w1, ev.y, a1y);
    a2x = fmaf(w2, ev.x, a2x); a2y = fmaf(w2, ev.y, a2y);
    a3x = fmaf(w3, ev.x, a3x); a3y = fmaf(w3, ev.y, a3y);
  }
  size_t base = ((size_t)(b*16) + ch) * (H_*E_);
  ctxp[base + 0*E_ + e0] = a0x; ctxp[base + 0*E_ + e0+1] = a0y;
  ctxp[base + 1*E_ + e0] = a1x; ctxp[base + 1*E_ + e0+1] = a1y;
  ctxp[base + 2*E_ + e0] = a2x; ctxp[base + 2*E_ + e0+1] = a2y;
  ctxp[base + 3*E_ + e0] = a3x; ctxp[base + 3*E_ + e0+1] = a3y;
}

// ---------------------------------------------------------------------------
// final: ctx[b][eo] = b_mha[eo] + sum_he (sum_ch ctxp[b][ch][he]) * W_mha[he][eo]
__global__ void k_final(const float* __restrict__ ctxp, const float* __restrict__ Wm,
                        const float* __restrict__ bm, float* __restrict__ out){
  int b = blockIdx.x;
  __shared__ float cp[2048];
  int tid = threadIdx.x;
  for (int i = tid; i < 2048; i += 256){
    float s = 0.f;
    for (int ch = 0; ch < 16; ch++) s += ctxp[((size_t)(b*16 + ch))*2048 + i];
    cp[i] = s;
  }
  __syncthreads();
  int eo = tid * 2;
  float acc0 = bm[eo], acc1 = bm[eo + 1];
  for (int he = 0; he < 2048; he++){
    float s = cp[he];
    float2 wv = *(const float2*)&Wm[(size_t)he*512 + eo];
    acc0 = fmaf(s, wv.x, acc0);
    acc1 = fmaf(s, wv.y, acc1);
  }
  out[(size_t)b*512 + eo]     = acc0;
  out[(size_t)b*512 + eo + 1] = acc1;
}

// ---------------------------------------------------------------------------
extern "C" void kernel_launch(void* const* d_in, const int* in_sizes, int n_in,
                              void* d_out, int out_size, void* d_ws, size_t ws_size,
                              hipStream_t stream){
  const float* enc    = (const float*)d_in[0];
  const int*   xl     = (const int*)  d_in[1];
  const float* dec    = (const float*)d_in[2];
  const float* awstep = (const float*)d_in[3];
  const float* We     = (const float*)d_in[4];
  const float* be     = (const float*)d_in[5];
  const float* Wd     = (const float*)d_in[6];
  const float* Wc     = (const float*)d_in[7];
  const float* convw  = (const float*)d_in[8];
  const float* Vv     = (const float*)d_in[9];
  const float* Wm     = (const float*)d_in[10];
  const float* bm     = (const float*)d_in[11];

  float* out_ctx = (float*)d_out;
  float* out_aw  = (float*)d_out + (size_t)B_ * E_;

  char* ws = (char*)d_ws;
  unsigned short* Wcomb = (unsigned short*)ws; ws += (size_t)H_*512*KTOT*2;  // 2,228,224
  float* dech      = (float*)ws; ws += (size_t)B_*H_*A_*4;                   //   131,072
  float* conv_feat = (float*)ws; ws += (size_t)B_*T_*H_*C_*4;                // 5,120,000
  float* energy    = (float*)ws; ws += (size_t)B_*T_*H_*4;                   //   512,000
  float* ctxp      = (float*)ws; ws += (size_t)B_*16*H_*E_*4;                // 2,097,152

  k_wcomb  <<<dim3(NKS, 16, H_), dim3(32, 8), 0, stream>>>(We, Wc, Wcomb);
  k_dec    <<<dim3(B_*H_),       dim3(256),   0, stream>>>(dec, Wd, be, dech);
  k_conv   <<<dim3(8, H_, B_),   dim3(256),   0, stream>>>(awstep, convw, conv_feat);
  k_energy <<<dim3(32, B_),      dim3(512),   0, stream>>>(enc, Wcomb, conv_feat, dech, Vv, xl, energy);
  k_softmax<<<dim3(H_, B_),      dim3(256),   0, stream>>>(energy, out_aw);
  k_ctxp   <<<dim3(16, B_),      dim3(256),   0, stream>>>(enc, out_aw, ctxp);
  k_final  <<<dim3(B_),          dim3(256),   0, stream>>>(ctxp, Wm, bm, out_ctx);
}

// Round 2
// 302.459 us; speedup vs baseline: 1.4529x; 1.4529x over previous
//
#include <hip/hip_runtime.h>

typedef __attribute__((ext_vector_type(8))) short short8;
typedef __attribute__((ext_vector_type(4))) float f32x4;

#define B_ 16
#define T_ 2000
#define E_ 512
#define A_ 512
#define H_ 4
#define C_ 10
#define KW_ 201
#define KT 576      // 512 enc + 40 conv (4 heads x 10) + 24 zero pad
#define MROWS 2048  // padded T per batch
#define NKS 9       // 576 / 64

__device__ __forceinline__ unsigned short f2bf(float f){
  unsigned int u = __float_as_uint(f);
  u += 0x7FFFu + ((u >> 16) & 1u);   // round-to-nearest-even
  return (unsigned short)(u >> 16);
}

__device__ __forceinline__ float fast_tanh(float x){
  float e2 = __expf(2.f * x);
  return 1.f - __fdividef(2.f, e2 + 1.f);
}

__device__ __forceinline__ void gl16(const void* g, void* lds){
  __builtin_amdgcn_global_load_lds((const __attribute__((address_space(1))) void*)g,
                                   (__attribute__((address_space(3))) void*)lds, 16, 0, 0);
}

// ---------------------------------------------------------------------------
// Wcomb[n = h*512+a][k]: k<512 -> W_enc[h][k][a]; k=512+h'*10+c -> (h'==h)?W_conv[h][c][a]:0; else 0
__global__ void k_wcomb(const float* __restrict__ We, const float* __restrict__ Wc,
                        unsigned short* __restrict__ Wcomb){
  int k0 = blockIdx.x * 32, n0 = blockIdx.y * 32;
  int h = n0 >> 9, a0 = n0 & 511;
  __shared__ float t[32][33];
  int tx = threadIdx.x, ty = threadIdx.y; // 32 x 8
  for (int i = ty; i < 32; i += 8){
    int k = k0 + i;
    float v = 0.f;
    if (k < 512) {
      v = We[((size_t)(h*512) + k)*512 + a0 + tx];
    } else if (k < 552) {
      int j = k - 512, hp = j / 10, c = j % 10;
      if (hp == h) v = Wc[(size_t)(h*10 + c)*512 + a0 + tx];
    }
    t[i][tx] = v;
  }
  __syncthreads();
  for (int i = ty; i < 32; i += 8){
    Wcomb[((size_t)n0 + i)*KT + k0 + tx] = f2bf(t[tx][i]);
  }
}

// ---------------------------------------------------------------------------
// dech[b][h][a] = b_enc[h][a] + sum_d dec_out[b][d] * W_dec[h][d][a]
__global__ void k_dec(const float* __restrict__ dec, const float* __restrict__ Wd,
                      const float* __restrict__ be, float* __restrict__ dech){
  int bh = blockIdx.x; int b = bh >> 2, h = bh & 3;
  int a0 = threadIdx.x * 2;
  float acc0 = be[h*512 + a0], acc1 = be[h*512 + a0 + 1];
  const float* w = Wd + (size_t)h*512*512;
  const float* dv = dec + b*512;
  for (int d = 0; d < 512; d++){
    float x = dv[d];
    acc0 = fmaf(x, w[(size_t)d*512 + a0],     acc0);
    acc1 = fmaf(x, w[(size_t)d*512 + a0 + 1], acc1);
  }
  dech[(size_t)bh*512 + a0]     = acc0;
  dech[(size_t)bh*512 + a0 + 1] = acc1;
}

// ---------------------------------------------------------------------------
// conv_feat[b][t][h*10+c] = sum_k aw_step[b][t+k-100][h] * conv_w[h*10+c][0][k]
#define TCH 250
__global__ void k_conv(const float* __restrict__ aw_step, const float* __restrict__ conv_w,
                       float* __restrict__ conv_feat){
  int tc = blockIdx.x, h = blockIdx.y, b = blockIdx.z;
  int t0 = tc * TCH;
  __shared__ float awl[TCH + 200];
  __shared__ float wl[C_][KW_];
  int tid = threadIdx.x;
  for (int i = tid; i < TCH + 200; i += 256){
    int t = t0 - 100 + i;
    awl[i] = (t >= 0 && t < T_) ? aw_step[((size_t)b*T_ + t)*H_ + h] : 0.f;
  }
  for (int i = tid; i < C_*KW_; i += 256){
    wl[i/KW_][i%KW_] = conv_w[(size_t)(h*C_ + i/KW_)*KW_ + i%KW_];
  }
  __syncthreads();
  for (int o = tid; o < TCH*C_; o += 256){
    int c = o / TCH, tl = o % TCH;
    float s = 0.f;
    #pragma unroll 4
    for (int k = 0; k < KW_; k++) s = fmaf(awl[tl + k], wl[c][k], s);
    conv_feat[((size_t)b*T_ + t0 + tl)*(H_*C_) + h*C_ + c] = s;
  }
}

// ---------------------------------------------------------------------------
// Abf[b][row<2048][k<576] bf16: k<512 enc, 512..551 conv_feat, else 0; rows>=2000 zero
__global__ void k_prepA(const float* __restrict__ enc, const float* __restrict__ cf,
                        unsigned short* __restrict__ Abf){
  int b = blockIdx.y;
  int r0 = blockIdx.x * 16;
  int tid = threadIdx.x;
  for (int idx = tid; idx < 16*144; idx += 256){
    int row = idx / 144, g = idx % 144;
    int t = r0 + row;
    float4 v = make_float4(0.f,0.f,0.f,0.f);
    if (t < T_){
      if (g < 128)      v = *(const float4*)&enc[((size_t)b*T_ + t)*E_ + g*4];
      else if (g < 138) v = *(const float4*)&cf[((size_t)b*T_ + t)*(H_*C_) + (g-128)*4];
    }
    ushort4 u; u.x = f2bf(v.x); u.y = f2bf(v.y); u.z = f2bf(v.z); u.w = f2bf(v.w);
    *(ushort4*)&Abf[((size_t)b*MROWS + t < (size_t)b*MROWS + t ? 0 : 0) + ((size_t)b*MROWS + r0 + row)*KT + g*4] = u;
  }
}

// ---------------------------------------------------------------------------
// m97-structure GEMM: part[b][t][h][p2] = sum_{a in 64-chunk} tanh(proj + dec)*V
__global__ __launch_bounds__(256, 3) void k_energy(
    const unsigned short* __restrict__ Abf, const unsigned short* __restrict__ Wb,
    const float* __restrict__ dech, const float* __restrict__ Vv,
    float* __restrict__ part)
{
  __shared__ __align__(16) unsigned short As[128*64];  // 16 KB linear [row][64]
  __shared__ __align__(16) unsigned short Bs[128*64];  // 16 KB linear [n][64]

  int hw = blockIdx.x;
  int logical = (hw & 7)*512 + (hw >> 3);   // XCD-contiguous chunks (4096 % 8 == 0)
  int mt = logical >> 4, nt = logical & 15;
  int b = mt >> 4, trow0 = (mt & 15)*128;
  int h = nt >> 2;

  const char* Ag = (const char*)(Abf + ((size_t)b*MROWS + trow0)*KT);
  const char* Bg = (const char*)(Wb + (size_t)nt*128*KT);

  int tid = threadIdx.x, lane = tid & 63, w = tid >> 6;
  int wm = w >> 1, wn = w & 1;

  f32x4 acc[4][4];
  #pragma unroll
  for (int m = 0; m < 4; m++)
    #pragma unroll
    for (int q = 0; q < 4; q++) acc[m][q] = (f32x4){0.f,0.f,0.f,0.f};

  for (int ks = 0; ks < NKS; ks++){
    __syncthreads();
    #pragma unroll
    for (int j = 0; j < 4; j++){
      int base = (w*4 + j)*1024;            // wave-uniform LDS byte base
      int off  = base + lane*16;            // this lane's tile byte
      int row  = off >> 7, colb = off & 127;
      gl16(Ag + (size_t)row*(KT*2) + ks*128 + colb, (char*)As + base);
      gl16(Bg + (size_t)row*(KT*2) + ks*128 + colb, (char*)Bs + base);
    }
    __syncthreads();
    short8 af[2][4];
    #pragma unroll
    for (int kk = 0; kk < 2; kk++)
      #pragma unroll
      for (int m = 0; m < 4; m++)
        af[kk][m] = *(const short8*)&As[(wm*64 + m*16 + (lane & 15))*64 + kk*32 + (lane >> 4)*8];
    #pragma unroll
    for (int kk = 0; kk < 2; kk++){
      #pragma unroll
      for (int q = 0; q < 4; q++){
        short8 bf = *(const short8*)&Bs[(wn*64 + q*16 + (lane & 15))*64 + kk*32 + (lane >> 4)*8];
        #pragma unroll
        for (int m = 0; m < 4; m++)
          acc[m][q] = __builtin_amdgcn_mfma_f32_16x16x32_bf16(af[kk][m], bf, acc[m][q], 0, 0, 0);
      }
    }
  }

  // epilogue: + dec bias, tanh, *V, reduce over this block's 64 a-cols per wave
  float dv[4], vv[4];
  int a0 = (nt & 3)*128 + wn*64;
  #pragma unroll
  for (int q = 0; q < 4; q++){
    int a = a0 + q*16 + (lane & 15);
    dv[q] = dech[(size_t)(b*H_ + h)*A_ + a];
    vv[q] = Vv[h*A_ + a];
  }
  int p2 = (nt & 3)*2 + wn;
  #pragma unroll
  for (int m = 0; m < 4; m++){
    #pragma unroll
    for (int r = 0; r < 4; r++){
      float ps = 0.f;
      #pragma unroll
      for (int q = 0; q < 4; q++)
        ps = fmaf(fast_tanh(acc[m][q][r] + dv[q]), vv[q], ps);
      ps += __shfl_xor(ps, 1);
      ps += __shfl_xor(ps, 2);
      ps += __shfl_xor(ps, 4);
      ps += __shfl_xor(ps, 8);
      if ((lane & 15) == 0){
        int t = trow0 + wm*64 + m*16 + (lane >> 4)*4 + r;
        if (t < T_) part[(((size_t)b*T_ + t)*H_ + h)*8 + p2] = ps;
      }
    }
  }
}

// ---------------------------------------------------------------------------
// softmax over T per (b,h); sums 8 partials, applies mask (zeroed energies kept)
__global__ void k_softmax(const float* __restrict__ part, const int* __restrict__ x_lens,
                          float* __restrict__ aw){
  int h = blockIdx.x, b = blockIdx.y;
  __shared__ float sh[T_];
  __shared__ float red[8];
  int tid = threadIdx.x;
  int xl = x_lens[b];
  float mx = -1e30f;
  for (int t = tid; t < T_; t += 256){
    float e = 0.f;
    if (t < xl){
      const float4* pp = (const float4*)&part[(((size_t)b*T_ + t)*H_ + h)*8];
      float4 v0 = pp[0], v1 = pp[1];
      e = (v0.x+v0.y+v0.z+v0.w) + (v1.x+v1.y+v1.z+v1.w);
    }
    sh[t] = e;
    mx = fmaxf(mx, e);
  }
  #pragma unroll
  for (int o = 32; o; o >>= 1) mx = fmaxf(mx, __shfl_xor(mx, o));
  if ((tid & 63) == 0) red[tid >> 6] = mx;
  __syncthreads();
  mx = fmaxf(fmaxf(red[0], red[1]), fmaxf(red[2], red[3]));
  float sm = 0.f;
  for (int t = tid; t < T_; t += 256){
    float ex = __expf(sh[t] - mx);
    sh[t] = ex;
    sm += ex;
  }
  #pragma unroll
  for (int o = 32; o; o >>= 1) sm += __shfl_xor(sm, o);
  if ((tid & 63) == 0) red[4 + (tid >> 6)] = sm;
  __syncthreads();
  sm = red[4] + red[5] + red[6] + red[7];
  float inv = 1.f / sm;
  for (int t = tid; t < T_; t += 256){
    aw[((size_t)b*T_ + t)*H_ + h] = sh[t] * inv;
  }
}

// ---------------------------------------------------------------------------
// partial context: ctxp[b][ch][h][e] = sum_{t in chunk} enc[b][t][e]*aw[b][t][h]
#define CCH 125
__global__ void k_ctxp(const float* __restrict__ enc, const float* __restrict__ aw,
                       float* __restrict__ ctxp){
  int ch = blockIdx.x, b = blockIdx.y;
  int t0 = ch * CCH;
  __shared__ float awl[CCH * 4];
  int tid = threadIdx.x;
  for (int i = tid; i < CCH*4; i += 256)
    awl[i] = aw[((size_t)b*T_ + t0)*H_ + i];
  __syncthreads();
  int e0 = tid * 2;
  float a0x=0,a0y=0,a1x=0,a1y=0,a2x=0,a2y=0,a3x=0,a3y=0;
  for (int tl = 0; tl < CCH; tl++){
    float2 ev = *(const float2*)&enc[((size_t)b*T_ + t0 + tl)*E_ + e0];
    float w0 = awl[tl*4+0], w1 = awl[tl*4+1], w2 = awl[tl*4+2], w3 = awl[tl*4+3];
    a0x = fmaf(w0, ev.x, a0x); a0y = fmaf(w0, ev.y, a0y);
    a1x = fmaf(w1, ev.x, a1x); a1y = fmaf(w1, ev.y, a1y);
    a2x = fmaf(w2, ev.x, a2x); a2y = fmaf(w2, ev.y, a2y);
    a3x = fmaf(w3, ev.x, a3x); a3y = fmaf(w3, ev.y, a3y);
  }
  size_t base = ((size_t)(b*16) + ch) * (H_*E_);
  ctxp[base + 0*E_ + e0] = a0x; ctxp[base + 0*E_ + e0+1] = a0y;
  ctxp[base + 1*E_ + e0] = a1x; ctxp[base + 1*E_ + e0+1] = a1y;
  ctxp[base + 2*E_ + e0] = a2x; ctxp[base + 2*E_ + e0+1] = a2y;
  ctxp[base + 3*E_ + e0] = a3x; ctxp[base + 3*E_ + e0+1] = a3y;
}

// ---------------------------------------------------------------------------
// final: ctx[b][eo] = b_mha[eo] + sum_he (sum_ch ctxp[b][ch][he]) * W_mha[he][eo]
__global__ void k_final(const float* __restrict__ ctxp, const float* __restrict__ Wm,
                        const float* __restrict__ bm, float* __restrict__ out){
  int b = blockIdx.x;
  __shared__ float cp[2048];
  int tid = threadIdx.x;
  for (int i = tid; i < 2048; i += 256){
    float s = 0.f;
    for (int ch = 0; ch < 16; ch++) s += ctxp[((size_t)(b*16 + ch))*2048 + i];
    cp[i] = s;
  }
  __syncthreads();
  int eo = tid * 2;
  float acc0 = bm[eo], acc1 = bm[eo + 1];
  for (int he = 0; he < 2048; he++){
    float s = cp[he];
    float2 wv = *(const float2*)&Wm[(size_t)he*512 + eo];
    acc0 = fmaf(s, wv.x, acc0);
    acc1 = fmaf(s, wv.y, acc1);
  }
  out[(size_t)b*512 + eo]     = acc0;
  out[(size_t)b*512 + eo + 1] = acc1;
}

// ---------------------------------------------------------------------------
extern "C" void kernel_launch(void* const* d_in, const int* in_sizes, int n_in,
                              void* d_out, int out_size, void* d_ws, size_t ws_size,
                              hipStream_t stream){
  const float* enc    = (const float*)d_in[0];
  const int*   xl     = (const int*)  d_in[1];
  const float* dec    = (const float*)d_in[2];
  const float* awstep = (const float*)d_in[3];
  const float* We     = (const float*)d_in[4];
  const float* be     = (const float*)d_in[5];
  const float* Wd     = (const float*)d_in[6];
  const float* Wc     = (const float*)d_in[7];
  const float* convw  = (const float*)d_in[8];
  const float* Vv     = (const float*)d_in[9];
  const float* Wm     = (const float*)d_in[10];
  const float* bm     = (const float*)d_in[11];

  float* out_ctx = (float*)d_out;
  float* out_aw  = (float*)d_out + (size_t)B_ * E_;

  char* ws = (char*)d_ws;
  unsigned short* Wcomb = (unsigned short*)ws; ws += (size_t)2048*KT*2;        //  2,359,296
  unsigned short* Abf   = (unsigned short*)ws; ws += (size_t)B_*MROWS*KT*2;    // 37,748,736
  float* dech      = (float*)ws; ws += (size_t)B_*H_*A_*4;                     //    131,072
  float* conv_feat = (float*)ws; ws += (size_t)B_*T_*H_*C_*4;                  //  5,120,000
  float* part      = (float*)ws; ws += (size_t)B_*T_*H_*8*4;                   //  4,096,000
  float* ctxp      = (float*)ws; ws += (size_t)B_*16*H_*E_*4;                  //  2,097,152

  k_conv   <<<dim3(8, H_, B_), dim3(256),   0, stream>>>(awstep, convw, conv_feat);
  k_wcomb  <<<dim3(18, 64),    dim3(32, 8), 0, stream>>>(We, Wc, Wcomb);
  k_dec    <<<dim3(B_*H_),     dim3(256),   0, stream>>>(dec, Wd, be, dech);
  k_prepA  <<<dim3(128, B_),   dim3(256),   0, stream>>>(enc, conv_feat, Abf);
  k_energy <<<dim3(4096),      dim3(256),   0, stream>>>(Abf, Wcomb, dech, Vv, part);
  k_softmax<<<dim3(H_, B_),    dim3(256),   0, stream>>>(part, xl, out_aw);
  k_ctxp   <<<dim3(16, B_),    dim3(256),   0, stream>>>(enc, out_aw, ctxp);
  k_final  <<<dim3(B_),        dim3(256),   0, stream>>>(ctxp, Wm, bm, out_ctx);
}

// Round 3
// 265.919 us; speedup vs baseline: 1.6526x; 1.1374x over previous
//
#include <hip/hip_runtime.h>

typedef __attribute__((ext_vector_type(8))) short short8;
typedef __attribute__((ext_vector_type(4))) float f32x4;

#define B_ 16
#define T_ 2000
#define E_ 512
#define A_ 512
#define H_ 4
#define C_ 10
#define KW_ 201
#define KT 576      // 512 enc + 40 conv (4 heads x 10) + 24 zero pad
#define MROWS 2048  // padded T per batch
#define NKT 9       // 576 / 64 K-tiles

__device__ __forceinline__ unsigned short f2bf(float f){
  unsigned int u = __float_as_uint(f);
  u += 0x7FFFu + ((u >> 16) & 1u);   // round-to-nearest-even
  return (unsigned short)(u >> 16);
}
__device__ __forceinline__ float bf2f(unsigned short u){
  return __uint_as_float(((unsigned int)u) << 16);
}
__device__ __forceinline__ float fast_tanh(float x){
  float e2 = __expf(2.f * x);
  return 1.f - __fdividef(2.f, e2 + 1.f);
}
__device__ __forceinline__ void gl16(const void* g, void* lds){
  __builtin_amdgcn_global_load_lds((const __attribute__((address_space(1))) void*)g,
                                   (__attribute__((address_space(3))) void*)lds, 16, 0, 0);
}

// ---------------------------------------------------------------------------
// Wcomb[n = h*512+a][k]: k<512 -> W_enc[h][k][a]; k=512+h'*10+c -> (h'==h)?W_conv[h][c][a]:0; else 0
__global__ void k_wcomb(const float* __restrict__ We, const float* __restrict__ Wc,
                        unsigned short* __restrict__ Wcomb){
  int k0 = blockIdx.x * 32, n0 = blockIdx.y * 32;
  int h = n0 >> 9, a0 = n0 & 511;
  __shared__ float t[32][33];
  int tx = threadIdx.x, ty = threadIdx.y; // 32 x 8
  for (int i = ty; i < 32; i += 8){
    int k = k0 + i;
    float v = 0.f;
    if (k < 512) {
      v = We[((size_t)(h*512) + k)*512 + a0 + tx];
    } else if (k < 552) {
      int j = k - 512, hp = j / 10, c = j % 10;
      if (hp == h) v = Wc[(size_t)(h*10 + c)*512 + a0 + tx];
    }
    t[i][tx] = v;
  }
  __syncthreads();
  for (int i = ty; i < 32; i += 8){
    Wcomb[((size_t)n0 + i)*KT + k0 + tx] = f2bf(t[tx][i]);
  }
}

// ---------------------------------------------------------------------------
// dech_p[dq][b*4+h][a] partial over d-chunk dq (bias folded into dq==0)
__global__ void k_dec(const float* __restrict__ dec, const float* __restrict__ Wd,
                      const float* __restrict__ be, float* __restrict__ dech_p){
  int bh = blockIdx.x, dq = blockIdx.y;
  int b = bh >> 2, h = bh & 3;
  int a0 = threadIdx.x * 2;
  float acc0 = 0.f, acc1 = 0.f;
  if (dq == 0){ acc0 = be[h*512 + a0]; acc1 = be[h*512 + a0 + 1]; }
  const float* w = Wd + (size_t)h*512*512 + (size_t)dq*128*512;
  const float* dv = dec + b*512 + dq*128;
  #pragma unroll 4
  for (int d = 0; d < 128; d++){
    float x = dv[d];
    acc0 = fmaf(x, w[(size_t)d*512 + a0],     acc0);
    acc1 = fmaf(x, w[(size_t)d*512 + a0 + 1], acc1);
  }
  dech_p[((size_t)dq*64 + bh)*512 + a0]     = acc0;
  dech_p[((size_t)dq*64 + bh)*512 + a0 + 1] = acc1;
}

// ---------------------------------------------------------------------------
// conv_feat[b][t][h*10+c] = sum_k aw_step[b][t+k-100][h] * conv_w[h*10+c][0][k]
#define TCH 250
__global__ void k_conv(const float* __restrict__ aw_step, const float* __restrict__ conv_w,
                       float* __restrict__ conv_feat){
  int tc = blockIdx.x, h = blockIdx.y, b = blockIdx.z;
  int t0 = tc * TCH;
  __shared__ float awl[TCH + 200];
  __shared__ float wl[C_][KW_];
  int tid = threadIdx.x;
  for (int i = tid; i < TCH + 200; i += 256){
    int t = t0 - 100 + i;
    awl[i] = (t >= 0 && t < T_) ? aw_step[((size_t)b*T_ + t)*H_ + h] : 0.f;
  }
  for (int i = tid; i < C_*KW_; i += 256){
    wl[i/KW_][i%KW_] = conv_w[(size_t)(h*C_ + i/KW_)*KW_ + i%KW_];
  }
  __syncthreads();
  for (int o = tid; o < TCH*C_; o += 256){
    int c = o / TCH, tl = o % TCH;
    float s = 0.f;
    #pragma unroll 4
    for (int k = 0; k < KW_; k++) s = fmaf(awl[tl + k], wl[c][k], s);
    conv_feat[((size_t)b*T_ + t0 + tl)*(H_*C_) + h*C_ + c] = s;
  }
}

// ---------------------------------------------------------------------------
// Abf[b][row<2048][k<576] bf16: k<512 enc, 512..551 conv_feat, else 0; rows>=2000 zero
__global__ void k_prepA(const float* __restrict__ enc, const float* __restrict__ cf,
                        unsigned short* __restrict__ Abf){
  int b = blockIdx.y;
  int r0 = blockIdx.x * 16;
  int tid = threadIdx.x;
  for (int idx = tid; idx < 16*144; idx += 256){
    int row = idx / 144, g = idx % 144;
    int t = r0 + row;
    float4 v = make_float4(0.f,0.f,0.f,0.f);
    if (t < T_){
      if (g < 128)      v = *(const float4*)&enc[((size_t)b*T_ + t)*E_ + g*4];
      else if (g < 138) v = *(const float4*)&cf[((size_t)b*T_ + t)*(H_*C_) + (g-128)*4];
    }
    ushort4 u; u.x = f2bf(v.x); u.y = f2bf(v.y); u.z = f2bf(v.z); u.w = f2bf(v.w);
    *(ushort4*)&Abf[((size_t)b*MROWS + r0 + row)*KT + g*4] = u;
  }
}

// ---------------------------------------------------------------------------
// 256x256 counted-vmcnt pipelined GEMM + tanh/V epilogue.
// part[b][t][h][p2] = sum over 64 a-cols of tanh(proj + dec)*V
__global__ __launch_bounds__(512, 2) void k_energy(
    const unsigned short* __restrict__ Abf, const unsigned short* __restrict__ Wb,
    const float* __restrict__ dech_p, const float* __restrict__ Vv,
    float* __restrict__ part)
{
  __shared__ __align__(16) unsigned short As[2*16384];  // 2 x [256][64] bf16, 64 KB
  __shared__ __align__(16) unsigned short Bs[2*16384];  // 2 x [256][64] bf16, 64 KB

  int hw = blockIdx.x;
  int logical = (hw & 7)*128 + (hw >> 3);   // XCD-contiguous (1024 % 8 == 0)
  int mt = logical >> 3, nt = logical & 7;
  int b = mt >> 3, trow0 = (mt & 7)*256;
  int h = nt >> 1;

  const char* Ag = (const char*)(Abf + ((size_t)b*MROWS + trow0)*KT);
  const char* Bg = (const char*)(Wb + (size_t)nt*256*KT);

  int tid = threadIdx.x, lane = tid & 63, w = tid >> 6;
  int wm = w >> 2, wn = w & 3;              // 2 M-waves x 4 N-waves

  // staging geometry: thread t covers (row = j*64 + t/8, slot = t%8) per 8KB issue
  int srow = tid >> 3;
  int sslot = (tid & 7) ^ (srow & 7);       // inverse-swizzled global slot
  size_t scol = (size_t)sslot * 16;
  int ldsw = w * 1024;                       // wave-uniform LDS byte base

  // read-side swizzled column bytes (per lane, per kk)
  int cx0 = (((lane >> 4) * 16)      ) ^ ((lane & 7) << 4);
  int cx1 = (((lane >> 4) * 16) + 64 ) ^ ((lane & 7) << 4);
  int arow = (wm*128 + (lane & 15)) * 128;  // byte offset of A row
  int brow = (wn*64  + (lane & 15)) * 128;

  f32x4 acc[8][4];
  #pragma unroll
  for (int m = 0; m < 8; m++)
    #pragma unroll
    for (int q = 0; q < 4; q++) acc[m][q] = (f32x4){0.f,0.f,0.f,0.f};

  #define STAGE(ks, buf) do {                                                  \
    char* la_ = (char*)(As + (buf)*16384) + ldsw;                              \
    char* lb_ = (char*)(Bs + (buf)*16384) + ldsw;                              \
    _Pragma("unroll")                                                          \
    for (int j_ = 0; j_ < 4; j_++)                                             \
      gl16(Ag + (size_t)(j_*64 + srow)*(KT*2) + (size_t)(ks)*128 + scol, la_ + j_*8192); \
    _Pragma("unroll")                                                          \
    for (int j_ = 0; j_ < 4; j_++)                                             \
      gl16(Bg + (size_t)(j_*64 + srow)*(KT*2) + (size_t)(ks)*128 + scol, lb_ + j_*8192); \
  } while(0)

  // prologue: stage tiles 0,1; wait for tile 0 only
  STAGE(0, 0);
  STAGE(1, 1);
  asm volatile("s_waitcnt vmcnt(8)" ::: "memory");
  __builtin_amdgcn_s_barrier();
  asm volatile("" ::: "memory");

  #pragma unroll
  for (int ks = 0; ks < NKT; ks++){
    const int cur = ks & 1;
    const char* Ac = (const char*)(As + cur*16384);
    const char* Bc = (const char*)(Bs + cur*16384);

    short8 bfr[4][2], alo[4][2], ahi[4][2];
    #pragma unroll
    for (int q = 0; q < 4; q++){
      bfr[q][0] = *(const short8*)(Bc + brow + q*2048 + cx0);
      bfr[q][1] = *(const short8*)(Bc + brow + q*2048 + cx1);
    }
    #pragma unroll
    for (int m = 0; m < 4; m++){
      alo[m][0] = *(const short8*)(Ac + arow + m*2048 + cx0);
      alo[m][1] = *(const short8*)(Ac + arow + m*2048 + cx1);
    }
    // MFMA half 1 (m0..3) — compiler inserts lgkm waits for true deps
    #pragma unroll
    for (int m = 0; m < 4; m++)
      #pragma unroll
      for (int q = 0; q < 4; q++){
        acc[m][q] = __builtin_amdgcn_mfma_f32_16x16x32_bf16(alo[m][0], bfr[q][0], acc[m][q], 0, 0, 0);
        acc[m][q] = __builtin_amdgcn_mfma_f32_16x16x32_bf16(alo[m][1], bfr[q][1], acc[m][q], 0, 0, 0);
      }
    #pragma unroll
    for (int m = 0; m < 4; m++){
      ahi[m][0] = *(const short8*)(Ac + arow + 8192 + m*2048 + cx0);
      ahi[m][1] = *(const short8*)(Ac + arow + 8192 + m*2048 + cx1);
    }
    // all reads of buf[cur] retired before barrier1, so staging into it is safe
    asm volatile("s_waitcnt lgkmcnt(0)" ::: "memory");
    __builtin_amdgcn_s_barrier();
    asm volatile("" ::: "memory");
    if (ks + 2 < NKT) STAGE(ks + 2, cur);
    __builtin_amdgcn_s_setprio(1);
    #pragma unroll
    for (int m = 0; m < 4; m++)
      #pragma unroll
      for (int q = 0; q < 4; q++){
        acc[4+m][q] = __builtin_amdgcn_mfma_f32_16x16x32_bf16(ahi[m][0], bfr[q][0], acc[4+m][q], 0, 0, 0);
        acc[4+m][q] = __builtin_amdgcn_mfma_f32_16x16x32_bf16(ahi[m][1], bfr[q][1], acc[4+m][q], 0, 0, 0);
      }
    __builtin_amdgcn_s_setprio(0);
    if (ks < NKT - 1){
      if (ks + 2 < NKT) asm volatile("s_waitcnt vmcnt(8)" ::: "memory");
      else              asm volatile("s_waitcnt vmcnt(0)" ::: "memory");
      __builtin_amdgcn_s_barrier();
      asm volatile("" ::: "memory");
    }
  }
  #undef STAGE

  // epilogue: + dec bias, tanh, *V, reduce over this wave's 64 a-cols
  float dv[4], vv[4];
  #pragma unroll
  for (int q = 0; q < 4; q++){
    int a = (nt & 1)*256 + wn*64 + q*16 + (lane & 15);
    int bh = b*4 + h;
    dv[q] = dech_p[((size_t)0*64 + bh)*512 + a] + dech_p[((size_t)1*64 + bh)*512 + a]
          + dech_p[((size_t)2*64 + bh)*512 + a] + dech_p[((size_t)3*64 + bh)*512 + a];
    vv[q] = Vv[h*A_ + a];
  }
  int p2 = (nt & 1)*4 + wn;
  #pragma unroll
  for (int m = 0; m < 8; m++){
    #pragma unroll
    for (int r = 0; r < 4; r++){
      float ps = 0.f;
      #pragma unroll
      for (int q = 0; q < 4; q++)
        ps = fmaf(fast_tanh(acc[m][q][r] + dv[q]), vv[q], ps);
      ps += __shfl_xor(ps, 1);
      ps += __shfl_xor(ps, 2);
      ps += __shfl_xor(ps, 4);
      ps += __shfl_xor(ps, 8);
      if ((lane & 15) == 0){
        int t = trow0 + wm*128 + m*16 + (lane >> 4)*4 + r;
        if (t < T_) part[(((size_t)b*T_ + t)*H_ + h)*8 + p2] = ps;
      }
    }
  }
}

// ---------------------------------------------------------------------------
// softmax over T per (b,h); sums 8 partials, applies mask (zeroed energies kept)
__global__ void k_softmax(const float* __restrict__ part, const int* __restrict__ x_lens,
                          float* __restrict__ aw){
  int h = blockIdx.x, b = blockIdx.y;
  __shared__ float sh[T_];
  __shared__ float red[8];
  int tid = threadIdx.x;
  int xl = x_lens[b];
  float mx = -1e30f;
  for (int t = tid; t < T_; t += 256){
    float e = 0.f;
    if (t < xl){
      const float4* pp = (const float4*)&part[(((size_t)b*T_ + t)*H_ + h)*8];
      float4 v0 = pp[0], v1 = pp[1];
      e = (v0.x+v0.y+v0.z+v0.w) + (v1.x+v1.y+v1.z+v1.w);
    }
    sh[t] = e;
    mx = fmaxf(mx, e);
  }
  #pragma unroll
  for (int o = 32; o; o >>= 1) mx = fmaxf(mx, __shfl_xor(mx, o));
  if ((tid & 63) == 0) red[tid >> 6] = mx;
  __syncthreads();
  mx = fmaxf(fmaxf(red[0], red[1]), fmaxf(red[2], red[3]));
  float sm = 0.f;
  for (int t = tid; t < T_; t += 256){
    float ex = __expf(sh[t] - mx);
    sh[t] = ex;
    sm += ex;
  }
  #pragma unroll
  for (int o = 32; o; o >>= 1) sm += __shfl_xor(sm, o);
  if ((tid & 63) == 0) red[4 + (tid >> 6)] = sm;
  __syncthreads();
  sm = red[4] + red[5] + red[6] + red[7];
  float inv = 1.f / sm;
  for (int t = tid; t < T_; t += 256){
    aw[((size_t)b*T_ + t)*H_ + h] = sh[t] * inv;
  }
}

// ---------------------------------------------------------------------------
// partial context from bf16 Abf: ctxp[b][ch][h][e] = sum_{t in chunk} Abf[b][t][e]*aw[b][t][h]
#define CCH 125
__global__ void k_ctxp(const unsigned short* __restrict__ Abf, const float* __restrict__ aw,
                       float* __restrict__ ctxp){
  int ch = blockIdx.x, b = blockIdx.y;
  int t0 = ch * CCH;
  __shared__ float awl[CCH * 4];
  int tid = threadIdx.x;
  for (int i = tid; i < CCH*4; i += 256)
    awl[i] = aw[((size_t)b*T_ + t0)*H_ + i];
  __syncthreads();
  int e0 = tid * 2;
  float a0x=0,a0y=0,a1x=0,a1y=0,a2x=0,a2y=0,a3x=0,a3y=0;
  for (int tl = 0; tl < CCH; tl++){
    uint uv = *(const uint*)&Abf[((size_t)b*MROWS + t0 + tl)*KT + e0];
    float evx = __uint_as_float(uv << 16);
    float evy = __uint_as_float(uv & 0xFFFF0000u);
    float w0 = awl[tl*4+0], w1 = awl[tl*4+1], w2 = awl[tl*4+2], w3 = awl[tl*4+3];
    a0x = fmaf(w0, evx, a0x); a0y = fmaf(w0, evy, a0y);
    a1x = fmaf(w1, evx, a1x); a1y = fmaf(w1, evy, a1y);
    a2x = fmaf(w2, evx, a2x); a2y = fmaf(w2, evy, a2y);
    a3x = fmaf(w3, evx, a3x); a3y = fmaf(w3, evy, a3y);
  }
  size_t base = ((size_t)(b*16) + ch) * (H_*E_);
  ctxp[base + 0*E_ + e0] = a0x; ctxp[base + 0*E_ + e0+1] = a0y;
  ctxp[base + 1*E_ + e0] = a1x; ctxp[base + 1*E_ + e0+1] = a1y;
  ctxp[base + 2*E_ + e0] = a2x; ctxp[base + 2*E_ + e0+1] = a2y;
  ctxp[base + 3*E_ + e0] = a3x; ctxp[base + 3*E_ + e0+1] = a3y;
}

// ---------------------------------------------------------------------------
// final: grid (B,8); block (b,g) computes 64 outputs eo = g*64..+63
__global__ void k_final(const float* __restrict__ ctxp, const float* __restrict__ Wm,
                        const float* __restrict__ bm, float* __restrict__ out){
  int b = blockIdx.x, g = blockIdx.y;
  __shared__ float cp[2048];
  __shared__ float red[4][64];
  int tid = threadIdx.x;
  for (int i = tid; i < 2048; i += 256){
    float s = 0.f;
    #pragma unroll 4
    for (int ch = 0; ch < 16; ch++) s += ctxp[((size_t)(b*16 + ch))*2048 + i];
    cp[i] = s;
  }
  __syncthreads();
  int e = tid & 63, p = tid >> 6;
  int eo = g*64 + e;
  float acc = 0.f;
  #pragma unroll 4
  for (int he = p*512; he < p*512 + 512; he++)
    acc = fmaf(cp[he], Wm[(size_t)he*512 + eo], acc);
  red[p][e] = acc;
  __syncthreads();
  if (tid < 64)
    out[(size_t)b*512 + g*64 + tid] = bm[g*64 + tid]
        + red[0][tid] + red[1][tid] + red[2][tid] + red[3][tid];
}

// ---------------------------------------------------------------------------
extern "C" void kernel_launch(void* const* d_in, const int* in_sizes, int n_in,
                              void* d_out, int out_size, void* d_ws, size_t ws_size,
                              hipStream_t stream){
  const float* enc    = (const float*)d_in[0];
  const int*   xl     = (const int*)  d_in[1];
  const float* dec    = (const float*)d_in[2];
  const float* awstep = (const float*)d_in[3];
  const float* We     = (const float*)d_in[4];
  const float* be     = (const float*)d_in[5];
  const float* Wd     = (const float*)d_in[6];
  const float* Wc     = (const float*)d_in[7];
  const float* convw  = (const float*)d_in[8];
  const float* Vv     = (const float*)d_in[9];
  const float* Wm     = (const float*)d_in[10];
  const float* bm     = (const float*)d_in[11];

  float* out_ctx = (float*)d_out;
  float* out_aw  = (float*)d_out + (size_t)B_ * E_;

  char* ws = (char*)d_ws;
  unsigned short* Wcomb = (unsigned short*)ws; ws += (size_t)2048*KT*2;        //  2,359,296
  unsigned short* Abf   = (unsigned short*)ws; ws += (size_t)B_*MROWS*KT*2;    // 37,748,736
  float* dech_p    = (float*)ws; ws += (size_t)4*64*512*4;                     //    524,288
  float* conv_feat = (float*)ws; ws += (size_t)B_*T_*H_*C_*4;                  //  5,120,000
  float* part      = (float*)ws; ws += (size_t)B_*T_*H_*8*4;                   //  4,096,000
  float* ctxp      = (float*)ws; ws += (size_t)B_*16*H_*E_*4;                  //  2,097,152

  k_conv   <<<dim3(8, H_, B_), dim3(256),   0, stream>>>(awstep, convw, conv_feat);
  k_wcomb  <<<dim3(18, 64),    dim3(32, 8), 0, stream>>>(We, Wc, Wcomb);
  k_dec    <<<dim3(64, 4),     dim3(256),   0, stream>>>(dec, Wd, be, dech_p);
  k_prepA  <<<dim3(128, B_),   dim3(256),   0, stream>>>(enc, conv_feat, Abf);
  k_energy <<<dim3(1024),      dim3(512),   0, stream>>>(Abf, Wcomb, dech_p, Vv, part);
  k_softmax<<<dim3(H_, B_),    dim3(256),   0, stream>>>(part, xl, out_aw);
  k_ctxp   <<<dim3(16, B_),    dim3(256),   0, stream>>>(Abf, out_aw, ctxp);
  k_final  <<<dim3(B_, 8),     dim3(256),   0, stream>>>(ctxp, Wm, bm, out_ctx);
}

// Round 4
// 219.619 us; speedup vs baseline: 2.0010x; 1.2108x over previous
//
#include <hip/hip_runtime.h>

typedef __attribute__((ext_vector_type(8))) short short8;
typedef __attribute__((ext_vector_type(4))) float f32x4;

#define B_ 16
#define T_ 2000
#define E_ 512
#define A_ 512
#define H_ 4
#define C_ 10
#define KW_ 201
#define KT 576      // 512 enc + 40 conv (4 heads x 10) + 24 zero pad
#define MROWS 2048  // padded T per batch
#define NKT 9       // 576 / 64 K-tiles

__device__ __forceinline__ unsigned short f2bf(float f){
  unsigned int u = __float_as_uint(f);
  u += 0x7FFFu + ((u >> 16) & 1u);   // round-to-nearest-even
  return (unsigned short)(u >> 16);
}
// Pade/continued-fraction tanh (levels 1,3,5,7,9) + clamp.
// |err| < 1e-5 for |x|<2, < 5e-4 for |x|<3.5; args here are ~N(0,0.65).
__device__ __forceinline__ float pade_tanh(float x){
  float t = x * x;
  float n = x * fmaf(t, t + 105.f, 945.f);         // x*(945 + 105 t + t^2)
  float d = fmaf(t, fmaf(t, 15.f, 420.f), 945.f);  // 945 + 420 t + 15 t^2
  float r = __fdividef(n, d);
  return fminf(1.f, fmaxf(-1.f, r));
}
__device__ __forceinline__ void gl16(const void* g, void* lds){
  __builtin_amdgcn_global_load_lds((const __attribute__((address_space(1))) void*)g,
                                   (__attribute__((address_space(3))) void*)lds, 16, 0, 0);
}
// 16-lane sum on the VALU pipe (DPP), leaves full sum in every lane of the row
#define DPP_ADD(x, ctrl) do { \
  int _y = __builtin_amdgcn_mov_dpp(__float_as_int(x), (ctrl), 0xf, 0xf, true); \
  (x) += __int_as_float(_y); } while(0)
#define ROW16_SUM(x) do { DPP_ADD(x,0xB1); DPP_ADD(x,0x4E); DPP_ADD(x,0x124); DPP_ADD(x,0x128); } while(0)

// ---------------------------------------------------------------------------
// Wcomb[n = h*512+a][k]: k<512 -> W_enc[h][k][a]; k=512+h'*10+c -> (h'==h)?W_conv[h][c][a]:0; else 0
__global__ void k_wcomb(const float* __restrict__ We, const float* __restrict__ Wc,
                        unsigned short* __restrict__ Wcomb){
  int k0 = blockIdx.x * 32, n0 = blockIdx.y * 32;
  int h = n0 >> 9, a0 = n0 & 511;
  __shared__ float t[32][33];
  int tx = threadIdx.x, ty = threadIdx.y; // 32 x 8
  for (int i = ty; i < 32; i += 8){
    int k = k0 + i;
    float v = 0.f;
    if (k < 512) {
      v = We[((size_t)(h*512) + k)*512 + a0 + tx];
    } else if (k < 552) {
      int j = k - 512, hp = j / 10, c = j % 10;
      if (hp == h) v = Wc[(size_t)(h*10 + c)*512 + a0 + tx];
    }
    t[i][tx] = v;
  }
  __syncthreads();
  for (int i = ty; i < 32; i += 8){
    Wcomb[((size_t)n0 + i)*KT + k0 + tx] = f2bf(t[tx][i]);
  }
}

// ---------------------------------------------------------------------------
// dech_p[dq][b*4+h][a] partial over d-chunk dq (bias folded into dq==0)
__global__ void k_dec(const float* __restrict__ dec, const float* __restrict__ Wd,
                      const float* __restrict__ be, float* __restrict__ dech_p){
  int bh = blockIdx.x, dq = blockIdx.y;
  int b = bh >> 2, h = bh & 3;
  int a0 = threadIdx.x * 2;
  float acc0 = 0.f, acc1 = 0.f;
  if (dq == 0){ acc0 = be[h*512 + a0]; acc1 = be[h*512 + a0 + 1]; }
  const float* w = Wd + (size_t)h*512*512 + (size_t)dq*128*512;
  const float* dv = dec + b*512 + dq*128;
  #pragma unroll 4
  for (int d = 0; d < 128; d++){
    float x = dv[d];
    acc0 = fmaf(x, w[(size_t)d*512 + a0],     acc0);
    acc1 = fmaf(x, w[(size_t)d*512 + a0 + 1], acc1);
  }
  dech_p[((size_t)dq*64 + bh)*512 + a0]     = acc0;
  dech_p[((size_t)dq*64 + bh)*512 + a0 + 1] = acc1;
}

// ---------------------------------------------------------------------------
// conv_feat[b][t][h*10+c] = sum_k aw_step[b][t+k-100][h] * conv_w[h*10+c][0][k]
// register sliding-window: thread owns 10 consecutive t for one channel c
#define TCH 250
__global__ void k_conv(const float* __restrict__ aw_step, const float* __restrict__ conv_w,
                       float* __restrict__ conv_feat){
  int tc = blockIdx.x, h = blockIdx.y, b = blockIdx.z;
  int t0 = tc * TCH;
  __shared__ float awl[TCH + 200];
  __shared__ float wl[C_ * KW_];
  int tid = threadIdx.x;
  for (int i = tid; i < TCH + 200; i += 256){
    int t = t0 - 100 + i;
    awl[i] = (t >= 0 && t < T_) ? aw_step[((size_t)b*T_ + t)*H_ + h] : 0.f;
  }
  for (int i = tid; i < C_*KW_; i += 256)
    wl[i] = conv_w[(size_t)h*C_*KW_ + i];
  __syncthreads();
  int c = tid % 10, g = tid / 10;
  bool act = g < 25;
  int tb = act ? g * 10 : 0;
  const float* wc = &wl[c * KW_];
  float acc[10], win[10];
  #pragma unroll
  for (int j = 0; j < 10; j++){ acc[j] = 0.f; win[j] = awl[tb + j]; }
  // invariant at k: win[(j+k)%10] == awl[tb + j + k]
  for (int k0 = 0; k0 < 200; k0 += 10){
    #pragma unroll
    for (int u = 0; u < 10; u++){
      float wk = wc[k0 + u];
      #pragma unroll
      for (int j = 0; j < 10; j++)
        acc[j] = fmaf(win[(j + u) % 10], wk, acc[j]);
      win[u] = awl[tb + k0 + u + 10];
    }
  }
  { // k = 200
    float wk = wc[200];
    #pragma unroll
    for (int j = 0; j < 10; j++)
      acc[j] = fmaf(win[j], wk, acc[j]);
  }
  if (act){
    #pragma unroll
    for (int j = 0; j < 10; j++)
      conv_feat[((size_t)b*T_ + t0 + tb + j)*(H_*C_) + h*C_ + c] = acc[j];
  }
}

// ---------------------------------------------------------------------------
// Abf[b][row<2048][k<576] bf16: k<512 enc, 512..551 conv_feat, else 0; rows>=2000 zero
__global__ void k_prepA(const float* __restrict__ enc, const float* __restrict__ cf,
                        unsigned short* __restrict__ Abf){
  int b = blockIdx.y;
  int r0 = blockIdx.x * 16;
  int tid = threadIdx.x;
  for (int idx = tid; idx < 16*144; idx += 256){
    int row = idx / 144, g = idx % 144;
    int t = r0 + row;
    float4 v = make_float4(0.f,0.f,0.f,0.f);
    if (t < T_){
      if (g < 128)      v = *(const float4*)&enc[((size_t)b*T_ + t)*E_ + g*4];
      else if (g < 138) v = *(const float4*)&cf[((size_t)b*T_ + t)*(H_*C_) + (g-128)*4];
    }
    ushort4 u; u.x = f2bf(v.x); u.y = f2bf(v.y); u.z = f2bf(v.z); u.w = f2bf(v.w);
    *(ushort4*)&Abf[((size_t)b*MROWS + r0 + row)*KT + g*4] = u;
  }
}

// ---------------------------------------------------------------------------
// 256x256 counted-vmcnt pipelined GEMM + tanh/V epilogue.
// part[b][t][h][p2] = sum over 64 a-cols of tanh(proj + dec)*V
__global__ __launch_bounds__(512, 2) void k_energy(
    const unsigned short* __restrict__ Abf, const unsigned short* __restrict__ Wb,
    const float* __restrict__ dech_p, const float* __restrict__ Vv,
    float* __restrict__ part)
{
  __shared__ __align__(16) unsigned short As[2*16384];  // 2 x [256][64] bf16, 64 KB
  __shared__ __align__(16) unsigned short Bs[2*16384];  // 2 x [256][64] bf16, 64 KB

  int hw = blockIdx.x;
  int logical = (hw & 7)*128 + (hw >> 3);   // XCD-contiguous (1024 % 8 == 0)
  int mt = logical >> 3, nt = logical & 7;
  int b = mt >> 3, trow0 = (mt & 7)*256;
  int h = nt >> 1;

  const char* Ag = (const char*)(Abf + ((size_t)b*MROWS + trow0)*KT);
  const char* Bg = (const char*)(Wb + (size_t)nt*256*KT);

  int tid = threadIdx.x, lane = tid & 63, w = tid >> 6;
  int wm = w >> 2, wn = w & 3;              // 2 M-waves x 4 N-waves

  // staging geometry: thread t covers (row = j*64 + t/8, slot = t%8) per 8KB issue
  int srow = tid >> 3;
  int sslot = (tid & 7) ^ (srow & 7);       // inverse-swizzled global slot
  size_t scol = (size_t)sslot * 16;
  int ldsw = w * 1024;                       // wave-uniform LDS byte base

  // read-side swizzled column bytes (per lane, per kk)
  int cx0 = (((lane >> 4) * 16)      ) ^ ((lane & 7) << 4);
  int cx1 = (((lane >> 4) * 16) + 64 ) ^ ((lane & 7) << 4);
  int arow = (wm*128 + (lane & 15)) * 128;  // byte offset of A row
  int brow = (wn*64  + (lane & 15)) * 128;

  // epilogue constants hoisted: they drain at the prologue vmcnt(8)
  float dv[4], vv[4];
  #pragma unroll
  for (int q = 0; q < 4; q++){
    int a = (nt & 1)*256 + wn*64 + q*16 + (lane & 15);
    int bh = b*4 + h;
    dv[q] = dech_p[((size_t)0*64 + bh)*512 + a] + dech_p[((size_t)1*64 + bh)*512 + a]
          + dech_p[((size_t)2*64 + bh)*512 + a] + dech_p[((size_t)3*64 + bh)*512 + a];
    vv[q] = Vv[h*A_ + a];
  }

  f32x4 acc[8][4];
  #pragma unroll
  for (int m = 0; m < 8; m++)
    #pragma unroll
    for (int q = 0; q < 4; q++) acc[m][q] = (f32x4){0.f,0.f,0.f,0.f};

  #define STAGE(ks, buf) do {                                                  \
    char* la_ = (char*)(As + (buf)*16384) + ldsw;                              \
    char* lb_ = (char*)(Bs + (buf)*16384) + ldsw;                              \
    _Pragma("unroll")                                                          \
    for (int j_ = 0; j_ < 4; j_++)                                             \
      gl16(Ag + (size_t)(j_*64 + srow)*(KT*2) + (size_t)(ks)*128 + scol, la_ + j_*8192); \
    _Pragma("unroll")                                                          \
    for (int j_ = 0; j_ < 4; j_++)                                             \
      gl16(Bg + (size_t)(j_*64 + srow)*(KT*2) + (size_t)(ks)*128 + scol, lb_ + j_*8192); \
  } while(0)

  // prologue: stage tiles 0,1; wait for tile 0 only
  STAGE(0, 0);
  STAGE(1, 1);
  asm volatile("s_waitcnt vmcnt(8)" ::: "memory");
  __builtin_amdgcn_s_barrier();
  asm volatile("" ::: "memory");

  #pragma unroll
  for (int ks = 0; ks < NKT; ks++){
    const int cur = ks & 1;
    const char* Ac = (const char*)(As + cur*16384);
    const char* Bc = (const char*)(Bs + cur*16384);

    short8 bfr[4][2], alo[4][2], ahi[4][2];
    #pragma unroll
    for (int q = 0; q < 4; q++){
      bfr[q][0] = *(const short8*)(Bc + brow + q*2048 + cx0);
      bfr[q][1] = *(const short8*)(Bc + brow + q*2048 + cx1);
    }
    #pragma unroll
    for (int m = 0; m < 4; m++){
      alo[m][0] = *(const short8*)(Ac + arow + m*2048 + cx0);
      alo[m][1] = *(const short8*)(Ac + arow + m*2048 + cx1);
    }
    // MFMA half 1 (m0..3) — compiler inserts lgkm waits for true deps
    #pragma unroll
    for (int m = 0; m < 4; m++)
      #pragma unroll
      for (int q = 0; q < 4; q++){
        acc[m][q] = __builtin_amdgcn_mfma_f32_16x16x32_bf16(alo[m][0], bfr[q][0], acc[m][q], 0, 0, 0);
        acc[m][q] = __builtin_amdgcn_mfma_f32_16x16x32_bf16(alo[m][1], bfr[q][1], acc[m][q], 0, 0, 0);
      }
    #pragma unroll
    for (int m = 0; m < 4; m++){
      ahi[m][0] = *(const short8*)(Ac + arow + 8192 + m*2048 + cx0);
      ahi[m][1] = *(const short8*)(Ac + arow + 8192 + m*2048 + cx1);
    }
    // all reads of buf[cur] retired before barrier1, so staging into it is safe
    asm volatile("s_waitcnt lgkmcnt(0)" ::: "memory");
    __builtin_amdgcn_s_barrier();
    asm volatile("" ::: "memory");
    if (ks + 2 < NKT) STAGE(ks + 2, cur);
    __builtin_amdgcn_s_setprio(1);
    #pragma unroll
    for (int m = 0; m < 4; m++)
      #pragma unroll
      for (int q = 0; q < 4; q++){
        acc[4+m][q] = __builtin_amdgcn_mfma_f32_16x16x32_bf16(ahi[m][0], bfr[q][0], acc[4+m][q], 0, 0, 0);
        acc[4+m][q] = __builtin_amdgcn_mfma_f32_16x16x32_bf16(ahi[m][1], bfr[q][1], acc[4+m][q], 0, 0, 0);
      }
    __builtin_amdgcn_s_setprio(0);
    if (ks < NKT - 1){
      if (ks + 2 < NKT) asm volatile("s_waitcnt vmcnt(8)" ::: "memory");
      else              asm volatile("s_waitcnt vmcnt(0)" ::: "memory");
      __builtin_amdgcn_s_barrier();
      asm volatile("" ::: "memory");
    }
  }
  #undef STAGE

  // epilogue: + dec bias, Pade tanh, *V, DPP row-sum over this wave's 64 a-cols
  int p2 = (nt & 1)*4 + wn;
  #pragma unroll
  for (int m = 0; m < 8; m++){
    #pragma unroll
    for (int r = 0; r < 4; r++){
      float ps = 0.f;
      #pragma unroll
      for (int q = 0; q < 4; q++)
        ps = fmaf(pade_tanh(acc[m][q][r] + dv[q]), vv[q], ps);
      ROW16_SUM(ps);
      if ((lane & 15) == 0){
        int t = trow0 + wm*128 + m*16 + (lane >> 4)*4 + r;
        if (t < T_) part[(((size_t)b*T_ + t)*H_ + h)*8 + p2] = ps;
      }
    }
  }
}

// ---------------------------------------------------------------------------
// softmax over T per (b,h); sums 8 partials, applies mask (zeroed energies kept)
__global__ void k_softmax(const float* __restrict__ part, const int* __restrict__ x_lens,
                          float* __restrict__ aw){
  int h = blockIdx.x, b = blockIdx.y;
  __shared__ float sh[T_];
  __shared__ float red[8];
  int tid = threadIdx.x;
  int xl = x_lens[b];
  float mx = -1e30f;
  for (int t = tid; t < T_; t += 256){
    float e = 0.f;
    if (t < xl){
      const float4* pp = (const float4*)&part[(((size_t)b*T_ + t)*H_ + h)*8];
      float4 v0 = pp[0], v1 = pp[1];
      e = (v0.x+v0.y+v0.z+v0.w) + (v1.x+v1.y+v1.z+v1.w);
    }
    sh[t] = e;
    mx = fmaxf(mx, e);
  }
  #pragma unroll
  for (int o = 32; o; o >>= 1) mx = fmaxf(mx, __shfl_xor(mx, o));
  if ((tid & 63) == 0) red[tid >> 6] = mx;
  __syncthreads();
  mx = fmaxf(fmaxf(red[0], red[1]), fmaxf(red[2], red[3]));
  float sm = 0.f;
  for (int t = tid; t < T_; t += 256){
    float ex = __expf(sh[t] - mx);
    sh[t] = ex;
    sm += ex;
  }
  #pragma unroll
  for (int o = 32; o; o >>= 1) sm += __shfl_xor(sm, o);
  if ((tid & 63) == 0) red[4 + (tid >> 6)] = sm;
  __syncthreads();
  sm = red[4] + red[5] + red[6] + red[7];
  float inv = 1.f / sm;
  for (int t = tid; t < T_; t += 256){
    aw[((size_t)b*T_ + t)*H_ + h] = sh[t] * inv;
  }
}

// ---------------------------------------------------------------------------
// partial context from bf16 Abf: ctxp[b][ch][h][e] = sum_{t in chunk} Abf[b][t][e]*aw[b][t][h]
#define CCH 125
__global__ void k_ctxp(const unsigned short* __restrict__ Abf, const float* __restrict__ aw,
                       float* __restrict__ ctxp){
  int ch = blockIdx.x, b = blockIdx.y;
  int t0 = ch * CCH;
  __shared__ float awl[CCH * 4];
  int tid = threadIdx.x;
  for (int i = tid; i < CCH*4; i += 256)
    awl[i] = aw[((size_t)b*T_ + t0)*H_ + i];
  __syncthreads();
  int e0 = tid * 2;
  float a0x=0,a0y=0,a1x=0,a1y=0,a2x=0,a2y=0,a3x=0,a3y=0;
  for (int tl = 0; tl < CCH; tl++){
    uint uv = *(const uint*)&Abf[((size_t)b*MROWS + t0 + tl)*KT + e0];
    float evx = __uint_as_float(uv << 16);
    float evy = __uint_as_float(uv & 0xFFFF0000u);
    float w0 = awl[tl*4+0], w1 = awl[tl*4+1], w2 = awl[tl*4+2], w3 = awl[tl*4+3];
    a0x = fmaf(w0, evx, a0x); a0y = fmaf(w0, evy, a0y);
    a1x = fmaf(w1, evx, a1x); a1y = fmaf(w1, evy, a1y);
    a2x = fmaf(w2, evx, a2x); a2y = fmaf(w2, evy, a2y);
    a3x = fmaf(w3, evx, a3x); a3y = fmaf(w3, evy, a3y);
  }
  size_t base = ((size_t)(b*16) + ch) * (H_*E_);
  ctxp[base + 0*E_ + e0] = a0x; ctxp[base + 0*E_ + e0+1] = a0y;
  ctxp[base + 1*E_ + e0] = a1x; ctxp[base + 1*E_ + e0+1] = a1y;
  ctxp[base + 2*E_ + e0] = a2x; ctxp[base + 2*E_ + e0+1] = a2y;
  ctxp[base + 3*E_ + e0] = a3x; ctxp[base + 3*E_ + e0+1] = a3y;
}

// ---------------------------------------------------------------------------
// final: grid (B,8); block (b,g) computes 64 outputs eo = g*64..+63
__global__ void k_final(const float* __restrict__ ctxp, const float* __restrict__ Wm,
                        const float* __restrict__ bm, float* __restrict__ out){
  int b = blockIdx.x, g = blockIdx.y;
  __shared__ float cp[2048];
  __shared__ float red[4][64];
  int tid = threadIdx.x;
  for (int i = tid; i < 2048; i += 256){
    float s = 0.f;
    #pragma unroll 4
    for (int ch = 0; ch < 16; ch++) s += ctxp[((size_t)(b*16 + ch))*2048 + i];
    cp[i] = s;
  }
  __syncthreads();
  int e = tid & 63, p = tid >> 6;
  int eo = g*64 + e;
  float acc = 0.f;
  #pragma unroll 4
  for (int he = p*512; he < p*512 + 512; he++)
    acc = fmaf(cp[he], Wm[(size_t)he*512 + eo], acc);
  red[p][e] = acc;
  __syncthreads();
  if (tid < 64)
    out[(size_t)b*512 + g*64 + tid] = bm[g*64 + tid]
        + red[0][tid] + red[1][tid] + red[2][tid] + red[3][tid];
}

// ---------------------------------------------------------------------------
extern "C" void kernel_launch(void* const* d_in, const int* in_sizes, int n_in,
                              void* d_out, int out_size, void* d_ws, size_t ws_size,
                              hipStream_t stream){
  const float* enc    = (const float*)d_in[0];
  const int*   xl     = (const int*)  d_in[1];
  const float* dec    = (const float*)d_in[2];
  const float* awstep = (const float*)d_in[3];
  const float* We     = (const float*)d_in[4];
  const float* be     = (const float*)d_in[5];
  const float* Wd     = (const float*)d_in[6];
  const float* Wc     = (const float*)d_in[7];
  const float* convw  = (const float*)d_in[8];
  const float* Vv     = (const float*)d_in[9];
  const float* Wm     = (const float*)d_in[10];
  const float* bm     = (const float*)d_in[11];

  float* out_ctx = (float*)d_out;
  float* out_aw  = (float*)d_out + (size_t)B_ * E_;

  char* ws = (char*)d_ws;
  unsigned short* Wcomb = (unsigned short*)ws; ws += (size_t)2048*KT*2;        //  2,359,296
  unsigned short* Abf   = (unsigned short*)ws; ws += (size_t)B_*MROWS*KT*2;    // 37,748,736
  float* dech_p    = (float*)ws; ws += (size_t)4*64*512*4;                     //    524,288
  float* conv_feat = (float*)ws; ws += (size_t)B_*T_*H_*C_*4;                  //  5,120,000
  float* part      = (float*)ws; ws += (size_t)B_*T_*H_*8*4;                   //  4,096,000
  float* ctxp      = (float*)ws; ws += (size_t)B_*16*H_*E_*4;                  //  2,097,152

  k_conv   <<<dim3(8, H_, B_), dim3(256),   0, stream>>>(awstep, convw, conv_feat);
  k_wcomb  <<<dim3(18, 64),    dim3(32, 8), 0, stream>>>(We, Wc, Wcomb);
  k_dec    <<<dim3(64, 4),     dim3(256),   0, stream>>>(dec, Wd, be, dech_p);
  k_prepA  <<<dim3(128, B_),   dim3(256),   0, stream>>>(enc, conv_feat, Abf);
  k_energy <<<dim3(1024),      dim3(512),   0, stream>>>(Abf, Wcomb, dech_p, Vv, part);
  k_softmax<<<dim3(H_, B_),    dim3(256),   0, stream>>>(part, xl, out_aw);
  k_ctxp   <<<dim3(16, B_),    dim3(256),   0, stream>>>(Abf, out_aw, ctxp);
  k_final  <<<dim3(B_, 8),     dim3(256),   0, stream>>>(ctxp, Wm, bm, out_ctx);
}

// Round 5
// 210.950 us; speedup vs baseline: 2.0832x; 1.0411x over previous
//
#include <hip/hip_runtime.h>

typedef __attribute__((ext_vector_type(8))) short short8;
typedef __attribute__((ext_vector_type(4))) float f32x4;

#define B_ 16
#define T_ 2000
#define E_ 512
#define A_ 512
#define H_ 4
#define C_ 10
#define KW_ 201
#define KT 576      // 512 enc + 40 conv (4 heads x 10) + 24 zero pad
#define MROWS 2048  // padded T per batch
#define NKT 9       // 576 / 64 K-tiles

__device__ __forceinline__ unsigned short f2bf(float f){
  unsigned int u = __float_as_uint(f);
  u += 0x7FFFu + ((u >> 16) & 1u);   // round-to-nearest-even
  return (unsigned short)(u >> 16);
}
// Pade tanh + clamp; |err|<1e-5 for |x|<2; args here are ~N(0,0.65).
__device__ __forceinline__ float pade_tanh(float x){
  float t = x * x;
  float n = x * fmaf(t, t + 105.f, 945.f);
  float d = fmaf(t, fmaf(t, 15.f, 420.f), 945.f);
  float r = __fdividef(n, d);
  return fminf(1.f, fmaxf(-1.f, r));
}
__device__ __forceinline__ void gl16(const void* g, void* lds){
  __builtin_amdgcn_global_load_lds((const __attribute__((address_space(1))) void*)g,
                                   (__attribute__((address_space(3))) void*)lds, 16, 0, 0);
}
#define DPP_ADD(x, ctrl) do { \
  int _y = __builtin_amdgcn_mov_dpp(__float_as_int(x), (ctrl), 0xf, 0xf, true); \
  (x) += __int_as_float(_y); } while(0)
#define ROW16_SUM(x) do { DPP_ADD(x,0xB1); DPP_ADD(x,0x4E); DPP_ADD(x,0x124); DPP_ADD(x,0x128); } while(0)

// ---------------------------------------------------------------------------
// Fat preprocessing kernel: blocks [0,512) conv, [512,1664) wcomb, [1664,1920) dec
#define TCH 250
__global__ void k_pre(const float* __restrict__ aw_step, const float* __restrict__ conv_w,
                      float* __restrict__ conv_feat,
                      const float* __restrict__ We, const float* __restrict__ Wc,
                      unsigned short* __restrict__ Wcomb,
                      const float* __restrict__ dec, const float* __restrict__ Wd,
                      const float* __restrict__ be, float* __restrict__ dech_p){
  __shared__ float pool[2460];
  int bid = blockIdx.x, tid = threadIdx.x;
  if (bid < 512){
    // ---- conv: register sliding window, thread owns 10 t for one channel
    int tc = bid & 7, h = (bid >> 3) & 3, b = bid >> 5;
    int t0 = tc * TCH;
    float* awl = pool;          // [450]
    float* wl  = pool + 450;    // [2010]
    for (int i = tid; i < TCH + 200; i += 256){
      int t = t0 - 100 + i;
      awl[i] = (t >= 0 && t < T_) ? aw_step[((size_t)b*T_ + t)*H_ + h] : 0.f;
    }
    for (int i = tid; i < C_*KW_; i += 256)
      wl[i] = conv_w[(size_t)h*C_*KW_ + i];
    __syncthreads();
    int c = tid % 10, g = tid / 10;
    bool act = g < 25;
    int tb = act ? g * 10 : 0;
    const float* wc = &wl[c * KW_];
    float acc[10], win[10];
    #pragma unroll
    for (int j = 0; j < 10; j++){ acc[j] = 0.f; win[j] = awl[tb + j]; }
    for (int k0 = 0; k0 < 200; k0 += 10){
      #pragma unroll
      for (int u = 0; u < 10; u++){
        float wk = wc[k0 + u];
        #pragma unroll
        for (int j = 0; j < 10; j++)
          acc[j] = fmaf(win[(j + u) % 10], wk, acc[j]);
        win[u] = awl[tb + k0 + u + 10];
      }
    }
    float wk = wc[200];
    #pragma unroll
    for (int j = 0; j < 10; j++)
      acc[j] = fmaf(win[j], wk, acc[j]);
    if (act){
      #pragma unroll
      for (int j = 0; j < 10; j++)
        conv_feat[((size_t)b*T_ + t0 + tb + j)*(H_*C_) + h*C_ + c] = acc[j];
    }
  } else if (bid < 1664){
    // ---- wcomb: Wcomb[n=h*512+a][k] transpose-pack to bf16
    int j = bid - 512;
    int k0 = (j % 18) * 32, n0 = (j / 18) * 32;
    int h = n0 >> 9, a0 = n0 & 511;
    float (*tt)[33] = (float(*)[33])pool;
    int tx = tid & 31, ty = tid >> 5;   // 32 x 8
    for (int i = ty; i < 32; i += 8){
      int k = k0 + i;
      float v = 0.f;
      if (k < 512) {
        v = We[((size_t)(h*512) + k)*512 + a0 + tx];
      } else if (k < 552) {
        int jj = k - 512, hp = jj / 10, c = jj % 10;
        if (hp == h) v = Wc[(size_t)(h*10 + c)*512 + a0 + tx];
      }
      tt[i][tx] = v;
    }
    __syncthreads();
    for (int i = ty; i < 32; i += 8)
      Wcomb[((size_t)n0 + i)*KT + k0 + tx] = f2bf(tt[tx][i]);
  } else {
    // ---- dec partials: dech_p[dq][b*4+h][a]
    int j = bid - 1664;
    int bh = j & 63, dq = j >> 6;
    int a0 = tid * 2;
    int h = bh & 3;
    float acc0 = 0.f, acc1 = 0.f;
    if (dq == 0){ acc0 = be[h*512 + a0]; acc1 = be[h*512 + a0 + 1]; }
    const float* w = Wd + (size_t)h*512*512 + (size_t)dq*128*512;
    const float* dv = dec + (bh >> 2)*512 + dq*128;
    #pragma unroll 4
    for (int d = 0; d < 128; d++){
      float x = dv[d];
      acc0 = fmaf(x, w[(size_t)d*512 + a0],     acc0);
      acc1 = fmaf(x, w[(size_t)d*512 + a0 + 1], acc1);
    }
    dech_p[((size_t)dq*64 + bh)*512 + a0]     = acc0;
    dech_p[((size_t)dq*64 + bh)*512 + a0 + 1] = acc1;
  }
}

// ---------------------------------------------------------------------------
// Abf[b][row<2048][k<576] bf16: k<512 enc, 512..551 conv_feat, else 0
__global__ void k_prepA(const float* __restrict__ enc, const float* __restrict__ cf,
                        unsigned short* __restrict__ Abf){
  int b = blockIdx.y;
  int r0 = blockIdx.x * 16;
  int tid = threadIdx.x;
  for (int idx = tid; idx < 16*144; idx += 256){
    int row = idx / 144, g = idx % 144;
    int t = r0 + row;
    float4 v = make_float4(0.f,0.f,0.f,0.f);
    if (t < T_){
      if (g < 128)      v = *(const float4*)&enc[((size_t)b*T_ + t)*E_ + g*4];
      else if (g < 138) v = *(const float4*)&cf[((size_t)b*T_ + t)*(H_*C_) + (g-128)*4];
    }
    ushort4 u; u.x = f2bf(v.x); u.y = f2bf(v.y); u.z = f2bf(v.z); u.w = f2bf(v.w);
    *(ushort4*)&Abf[((size_t)b*MROWS + r0 + row)*KT + g*4] = u;
  }
}

// ---------------------------------------------------------------------------
// 256x256 8-phase counted-vmcnt GEMM + tanh/V epilogue (m201-style schedule).
// LDS: A = 2 halves x 2 dbuf x [128][64]bf16 (4x16KB), B same, total 128 KB.
__global__ __launch_bounds__(512, 2) void k_energy(
    const unsigned short* __restrict__ Abf, const unsigned short* __restrict__ Wb,
    const float* __restrict__ dech_p, const float* __restrict__ Vv,
    float* __restrict__ part)
{
  __shared__ __align__(16) char sAB[131072];

  int hw = blockIdx.x;
  int logical = (hw & 7)*128 + (hw >> 3);   // XCD-contiguous (1024 % 8 == 0)
  int mt = logical >> 3, nt = logical & 7;
  int b = mt >> 3, trow0 = (mt & 7)*256;
  int h = nt >> 1;

  const char* Ag = (const char*)(Abf + ((size_t)b*MROWS + trow0)*KT);
  const char* Bg = (const char*)(Wb + (size_t)nt*256*KT);

  int tid = threadIdx.x, lane = tid & 63, w = tid >> 6;
  int wm = w >> 2, wn = w & 3;              // 2 M-waves x 4 N-waves

  // staging geometry (inverse-swizzled global source, linear LDS dest)
  int srow = tid >> 3;                       // row 0..63 within 64-row sweep
  size_t scol = (size_t)(((tid & 7) ^ (srow & 7)) * 16);
  int wub = w * 1024;                        // wave-uniform LDS byte base

  // read-side swizzled column bytes
  int cx0 = (((lane >> 4) * 16)     ) ^ ((lane & 7) << 4);
  int cx1 = (((lane >> 4) * 16) + 64) ^ ((lane & 7) << 4);
  int aqb = wm*32768 + (lane & 15)*128;            // A: half(wm), row (lane&15)
  int bqb = 65536 + (wn >> 1)*32768 + ((wn & 1)*64 + (lane & 15))*128;

  // epilogue constants (drained by explicit vmcnt(0) before staging)
  float dv[4], vv[4];
  #pragma unroll
  for (int q = 0; q < 4; q++){
    int a = (nt & 1)*256 + wn*64 + q*16 + (lane & 15);
    int bh = b*4 + h;
    dv[q] = dech_p[((size_t)0*64 + bh)*512 + a] + dech_p[((size_t)1*64 + bh)*512 + a]
          + dech_p[((size_t)2*64 + bh)*512 + a] + dech_p[((size_t)3*64 + bh)*512 + a];
    vv[q] = Vv[h*A_ + a];
  }

  f32x4 acc[8][4];
  #pragma unroll
  for (int m = 0; m < 8; m++)
    #pragma unroll
    for (int q = 0; q < 4; q++) acc[m][q] = (f32x4){0.f,0.f,0.f,0.f};

  short8 bfr[4][2], af[2][2];

#define VMC4   asm volatile("s_waitcnt vmcnt(4)" ::: "memory")
#define VMC0   asm volatile("s_waitcnt vmcnt(0)" ::: "memory")
#define LGKM0  asm volatile("s_waitcnt lgkmcnt(0)" ::: "memory")
#define BARRIER do{ asm volatile("" ::: "memory"); __builtin_amdgcn_s_barrier(); asm volatile("" ::: "memory"); }while(0)
#define PH_MID  BARRIER; LGKM0; __builtin_amdgcn_sched_barrier(0); __builtin_amdgcn_s_setprio(1)
#define PH_END  __builtin_amdgcn_s_setprio(0); BARRIER

#define READ_B(buf) do{ _Pragma("unroll") for (int q = 0; q < 4; q++){            \
    bfr[q][0] = *(const short8*)(sAB + bqb + q*2048 + (buf)*16384 + cx0);         \
    bfr[q][1] = *(const short8*)(sAB + bqb + q*2048 + (buf)*16384 + cx1); } }while(0)
#define READ_A(mb, buf) do{ _Pragma("unroll") for (int i = 0; i < 2; i++){        \
    af[i][0] = *(const short8*)(sAB + aqb + ((mb)+i)*2048 + (buf)*16384 + cx0);   \
    af[i][1] = *(const short8*)(sAB + aqb + ((mb)+i)*2048 + (buf)*16384 + cx1); } }while(0)
#define MFMA8(mb) do{ _Pragma("unroll") for (int i = 0; i < 2; i++)               \
    _Pragma("unroll") for (int q = 0; q < 4; q++){                                \
    acc[(mb)+i][q] = __builtin_amdgcn_mfma_f32_16x16x32_bf16(af[i][0], bfr[q][0], acc[(mb)+i][q],0,0,0); \
    acc[(mb)+i][q] = __builtin_amdgcn_mfma_f32_16x16x32_bf16(af[i][1], bfr[q][1], acc[(mb)+i][q],0,0,0); } }while(0)

#define STG_A(tile, half, buf) do{                                                \
    const char* g_ = Ag + (size_t)((half)*128 + srow)*(KT*2) + (size_t)(tile)*128 + scol; \
    char* l_ = sAB + (half)*32768 + (buf)*16384 + wub;                            \
    gl16(g_, l_); gl16(g_ + (size_t)64*(KT*2), l_ + 8192); }while(0)
#define STG_B(tile, half, buf) do{                                                \
    const char* g_ = Bg + (size_t)((half)*128 + srow)*(KT*2) + (size_t)(tile)*128 + scol; \
    char* l_ = sAB + 65536 + (half)*32768 + (buf)*16384 + wub;                    \
    gl16(g_, l_); gl16(g_ + (size_t)64*(KT*2), l_ + 8192); }while(0)

// one ring iteration: tiles T0 (buf0) and T0+1 (buf1); stages A(T0+1),B(T0+2),A(T0+2),B(T0+3)
#define ITER(T0, DO9) do{                                                         \
    READ_B(0); READ_A(0,0); STG_A((T0)+1, 0, 1);           PH_MID; MFMA8(0); PH_END; \
    READ_A(2,0);            STG_A((T0)+1, 1, 1);           PH_MID; MFMA8(2); PH_END; \
    READ_A(4,0);            STG_B((T0)+2, 0, 0);           PH_MID; MFMA8(4); PH_END; \
    READ_A(6,0);            STG_B((T0)+2, 1, 0); VMC4;     PH_MID; MFMA8(6); PH_END; \
    READ_B(1); READ_A(0,1); STG_A((T0)+2, 0, 0);           PH_MID; MFMA8(0); PH_END; \
    READ_A(2,1);            STG_A((T0)+2, 1, 0);           PH_MID; MFMA8(2); PH_END; \
    READ_A(4,1);            if (DO9) STG_B((T0)+3, 0, 1);  PH_MID; MFMA8(4); PH_END; \
    READ_A(6,1);            if (DO9) STG_B((T0)+3, 1, 1); VMC4; PH_MID; MFMA8(6); PH_END; \
  }while(0)

  // prologue: drain dv/vv, stage A(0),B(0),B(1); wait A(0)+B(0)
  VMC0;
  STG_A(0,0,0); STG_A(0,1,0); STG_B(0,0,0); STG_B(0,1,0); STG_B(1,0,1); STG_B(1,1,1);
  VMC4; BARRIER;

  ITER(0, 1);
  ITER(2, 1);
  ITER(4, 1);
  ITER(6, 0);

  // tail tile 8 (buf0): everything must be resident
  VMC0; BARRIER;
  READ_B(0); READ_A(0,0); PH_MID; MFMA8(0); PH_END;
  READ_A(2,0);            PH_MID; MFMA8(2); PH_END;
  READ_A(4,0);            PH_MID; MFMA8(4); PH_END;
  READ_A(6,0);            PH_MID; MFMA8(6); PH_END;

  // epilogue: + dec bias, Pade tanh, *V, DPP row-sum over this wave's 64 a-cols
  int p2 = (nt & 1)*4 + wn;
  #pragma unroll
  for (int m = 0; m < 8; m++){
    #pragma unroll
    for (int r = 0; r < 4; r++){
      float ps = 0.f;
      #pragma unroll
      for (int q = 0; q < 4; q++)
        ps = fmaf(pade_tanh(acc[m][q][r] + dv[q]), vv[q], ps);
      ROW16_SUM(ps);
      if ((lane & 15) == 0){
        int t = trow0 + wm*128 + m*16 + (lane >> 4)*4 + r;
        if (t < T_) part[(((size_t)b*T_ + t)*H_ + h)*8 + p2] = ps;
      }
    }
  }
}

// ---------------------------------------------------------------------------
// softmax over T per (b,h); sums 8 partials, applies mask
__global__ void k_softmax(const float* __restrict__ part, const int* __restrict__ x_lens,
                          float* __restrict__ aw){
  int h = blockIdx.x, b = blockIdx.y;
  __shared__ float sh[T_];
  __shared__ float red[8];
  int tid = threadIdx.x;
  int xl = x_lens[b];
  float mx = -1e30f;
  for (int t = tid; t < T_; t += 256){
    float e = 0.f;
    if (t < xl){
      const float4* pp = (const float4*)&part[(((size_t)b*T_ + t)*H_ + h)*8];
      float4 v0 = pp[0], v1 = pp[1];
      e = (v0.x+v0.y+v0.z+v0.w) + (v1.x+v1.y+v1.z+v1.w);
    }
    sh[t] = e;
    mx = fmaxf(mx, e);
  }
  #pragma unroll
  for (int o = 32; o; o >>= 1) mx = fmaxf(mx, __shfl_xor(mx, o));
  if ((tid & 63) == 0) red[tid >> 6] = mx;
  __syncthreads();
  mx = fmaxf(fmaxf(red[0], red[1]), fmaxf(red[2], red[3]));
  float sm = 0.f;
  for (int t = tid; t < T_; t += 256){
    float ex = __expf(sh[t] - mx);
    sh[t] = ex;
    sm += ex;
  }
  #pragma unroll
  for (int o = 32; o; o >>= 1) sm += __shfl_xor(sm, o);
  if ((tid & 63) == 0) red[4 + (tid >> 6)] = sm;
  __syncthreads();
  sm = red[4] + red[5] + red[6] + red[7];
  float inv = 1.f / sm;
  for (int t = tid; t < T_; t += 256){
    aw[((size_t)b*T_ + t)*H_ + h] = sh[t] * inv;
  }
}

// ---------------------------------------------------------------------------
// partial context from bf16 Abf
#define CCH 125
__global__ void k_ctxp(const unsigned short* __restrict__ Abf, const float* __restrict__ aw,
                       float* __restrict__ ctxp){
  int ch = blockIdx.x, b = blockIdx.y;
  int t0 = ch * CCH;
  __shared__ float awl[CCH * 4];
  int tid = threadIdx.x;
  for (int i = tid; i < CCH*4; i += 256)
    awl[i] = aw[((size_t)b*T_ + t0)*H_ + i];
  __syncthreads();
  int e0 = tid * 2;
  float a0x=0,a0y=0,a1x=0,a1y=0,a2x=0,a2y=0,a3x=0,a3y=0;
  for (int tl = 0; tl < CCH; tl++){
    uint uv = *(const uint*)&Abf[((size_t)b*MROWS + t0 + tl)*KT + e0];
    float evx = __uint_as_float(uv << 16);
    float evy = __uint_as_float(uv & 0xFFFF0000u);
    float w0 = awl[tl*4+0], w1 = awl[tl*4+1], w2 = awl[tl*4+2], w3 = awl[tl*4+3];
    a0x = fmaf(w0, evx, a0x); a0y = fmaf(w0, evy, a0y);
    a1x = fmaf(w1, evx, a1x); a1y = fmaf(w1, evy, a1y);
    a2x = fmaf(w2, evx, a2x); a2y = fmaf(w2, evy, a2y);
    a3x = fmaf(w3, evx, a3x); a3y = fmaf(w3, evy, a3y);
  }
  size_t base = ((size_t)(b*16) + ch) * (H_*E_);
  ctxp[base + 0*E_ + e0] = a0x; ctxp[base + 0*E_ + e0+1] = a0y;
  ctxp[base + 1*E_ + e0] = a1x; ctxp[base + 1*E_ + e0+1] = a1y;
  ctxp[base + 2*E_ + e0] = a2x; ctxp[base + 2*E_ + e0+1] = a2y;
  ctxp[base + 3*E_ + e0] = a3x; ctxp[base + 3*E_ + e0+1] = a3y;
}

// ---------------------------------------------------------------------------
// final: grid (B,8); block (b,g) computes 64 outputs eo = g*64..+63
__global__ void k_final(const float* __restrict__ ctxp, const float* __restrict__ Wm,
                        const float* __restrict__ bm, float* __restrict__ out){
  int b = blockIdx.x, g = blockIdx.y;
  __shared__ float cp[2048];
  __shared__ float red[4][64];
  int tid = threadIdx.x;
  for (int i = tid; i < 2048; i += 256){
    float s = 0.f;
    #pragma unroll 4
    for (int ch = 0; ch < 16; ch++) s += ctxp[((size_t)(b*16 + ch))*2048 + i];
    cp[i] = s;
  }
  __syncthreads();
  int e = tid & 63, p = tid >> 6;
  int eo = g*64 + e;
  float acc = 0.f;
  #pragma unroll 4
  for (int he = p*512; he < p*512 + 512; he++)
    acc = fmaf(cp[he], Wm[(size_t)he*512 + eo], acc);
  red[p][e] = acc;
  __syncthreads();
  if (tid < 64)
    out[(size_t)b*512 + g*64 + tid] = bm[g*64 + tid]
        + red[0][tid] + red[1][tid] + red[2][tid] + red[3][tid];
}

// ---------------------------------------------------------------------------
extern "C" void kernel_launch(void* const* d_in, const int* in_sizes, int n_in,
                              void* d_out, int out_size, void* d_ws, size_t ws_size,
                              hipStream_t stream){
  const float* enc    = (const float*)d_in[0];
  const int*   xl     = (const int*)  d_in[1];
  const float* dec    = (const float*)d_in[2];
  const float* awstep = (const float*)d_in[3];
  const float* We     = (const float*)d_in[4];
  const float* be     = (const float*)d_in[5];
  const float* Wd     = (const float*)d_in[6];
  const float* Wc     = (const float*)d_in[7];
  const float* convw  = (const float*)d_in[8];
  const float* Vv     = (const float*)d_in[9];
  const float* Wm     = (const float*)d_in[10];
  const float* bm     = (const float*)d_in[11];

  float* out_ctx = (float*)d_out;
  float* out_aw  = (float*)d_out + (size_t)B_ * E_;

  char* ws = (char*)d_ws;
  unsigned short* Wcomb = (unsigned short*)ws; ws += (size_t)2048*KT*2;        //  2,359,296
  unsigned short* Abf   = (unsigned short*)ws; ws += (size_t)B_*MROWS*KT*2;    // 37,748,736
  float* dech_p    = (float*)ws; ws += (size_t)4*64*512*4;                     //    524,288
  float* conv_feat = (float*)ws; ws += (size_t)B_*T_*H_*C_*4;                  //  5,120,000
  float* part      = (float*)ws; ws += (size_t)B_*T_*H_*8*4;                   //  4,096,000
  float* ctxp      = (float*)ws; ws += (size_t)B_*16*H_*E_*4;                  //  2,097,152

  k_pre    <<<dim3(1920),    dim3(256), 0, stream>>>(awstep, convw, conv_feat,
                                                     We, Wc, Wcomb, dec, Wd, be, dech_p);
  k_prepA  <<<dim3(128, B_), dim3(256), 0, stream>>>(enc, conv_feat, Abf);
  k_energy <<<dim3(1024),    dim3(512), 0, stream>>>(Abf, Wcomb, dech_p, Vv, part);
  k_softmax<<<dim3(H_, B_),  dim3(256), 0, stream>>>(part, xl, out_aw);
  k_ctxp   <<<dim3(16, B_),  dim3(256), 0, stream>>>(Abf, out_aw, ctxp);
  k_final  <<<dim3(B_, 8),   dim3(256), 0, stream>>>(ctxp, Wm, bm, out_ctx);
}